// Round 1
// baseline (1642.765 us; speedup 1.0000x reference)
//
#include <hip/hip_runtime.h>
#include <hip/hip_bf16.h>
#include <math.h>

typedef __hip_bfloat16 bf16;
typedef __attribute__((ext_vector_type(8))) short bf16x8;   // 8 bf16 = 4 VGPRs (MFMA A/B frag)
typedef __attribute__((ext_vector_type(4))) float f32x4;    // MFMA C/D frag

__device__ __forceinline__ void glds16(const bf16* g, bf16* l) {
    __builtin_amdgcn_global_load_lds(
        (const __attribute__((address_space(1))) void*)g,
        (__attribute__((address_space(3))) void*)l, 16, 0, 0);
}

// ---------------------------------------------------------------------------
// Self-detecting convert: each wave inspects the tensor's first 128 ushorts.
// True bf16 N(0,1): no exponent >= 0x86 (|x|>=128). fp32 reinterpreted: even
// ushorts are low-mantissa halves, ~47% have exp>=0x86. Wave-uniform branch.
// (Empirically: inputs ARE fp32 — round1 NaN -> round2 finite proved it.)
// ---------------------------------------------------------------------------
__global__ __launch_bounds__(256)
void convert_to_bf16(const void* __restrict__ src, bf16* __restrict__ dst, long n) {
    const unsigned short* u16 = (const unsigned short*)src;
    int lane = threadIdx.x & 63;
    unsigned short u = u16[lane * 2];
    int e = (u >> 7) & 0xFF;
    int isf32 = __popcll(__ballot(e >= 0x86)) > 4;   // wave-uniform
    long i = ((long)blockIdx.x * 256 + threadIdx.x) * 8;
    if (i >= n) return;
    if (isf32) {
        const float* s = (const float*)src;
        bf16x8 o;
        #pragma unroll
        for (int j = 0; j < 8; j++) {
            bf16 b = (bf16)s[i + j];
            o[j] = *(short*)&b;
        }
        *(bf16x8*)(dst + i) = o;
    } else {
        *(bf16x8*)(dst + i) = *(const bf16x8*)((const bf16*)src + i);
    }
}

// ---------------------------------------------------------------------------
// GEMM: C[M][N] = clip?(A[M][K] @ B[N][K]^T). bf16 in, fp32 accum, OUT out.
// m97 structure: 128x128 tile, BK=32, global_load_lds width=16, 4 waves 2x2.
// OUT=bf16 for intermediates, OUT=float for the final output (d_out is fp32!).
// ---------------------------------------------------------------------------
template<bool CLIP, typename OUT>
__global__ __launch_bounds__(256)
void gemm_bt(const bf16* __restrict__ A, const bf16* __restrict__ B,
             OUT* __restrict__ C, int M, int N, int K) {
    __shared__ __align__(16) bf16 sA[128 * 32];
    __shared__ __align__(16) bf16 sB[128 * 32];
    const int tid  = threadIdx.x;
    const int lane = tid & 63;
    const int wave = tid >> 6;
    const int wm   = wave >> 1;
    const int wn   = wave & 1;
    const int row  = lane & 15;
    const int quad = lane >> 4;
    const int bn = blockIdx.x, bm = blockIdx.y;

    const int r  = tid >> 2;            // 0..63
    const int kc = (tid & 3) * 8;       // 0,8,16,24
    const bf16* gA = A + (size_t)(bm * 128 + r) * K + kc;
    const bf16* gB = B + (size_t)(bn * 128 + r) * K + kc;
    bf16* lA = sA + tid * 8;            // contiguous in tid => glds-compatible
    bf16* lB = sB + tid * 8;

    f32x4 acc[4][4] = {};

    for (int kt = 0; kt < K; kt += 32) {
        glds16(gA + kt,                    lA);
        glds16(gA + kt + (size_t)64 * K,   lA + 2048);
        glds16(gB + kt,                    lB);
        glds16(gB + kt + (size_t)64 * K,   lB + 2048);
        __syncthreads();
        bf16x8 af[4], bfr[4];
        #pragma unroll
        for (int mt = 0; mt < 4; mt++)
            af[mt] = *(const bf16x8*)(sA + (wm * 64 + mt * 16 + row) * 32 + quad * 8);
        #pragma unroll
        for (int nt = 0; nt < 4; nt++)
            bfr[nt] = *(const bf16x8*)(sB + (wn * 64 + nt * 16 + row) * 32 + quad * 8);
        #pragma unroll
        for (int mt = 0; mt < 4; mt++)
            #pragma unroll
            for (int nt = 0; nt < 4; nt++)
                acc[mt][nt] = __builtin_amdgcn_mfma_f32_16x16x32_bf16(
                    af[mt], bfr[nt], acc[mt][nt], 0, 0, 0);
        __syncthreads();
    }

    #pragma unroll
    for (int mt = 0; mt < 4; mt++) {
        #pragma unroll
        for (int nt = 0; nt < 4; nt++) {
            #pragma unroll
            for (int v = 0; v < 4; v++) {
                float val = acc[mt][nt][v];
                if (CLIP) val = fminf(fmaxf(val, -8.0f), 8.0f);
                // C/D layout: col = lane&15, row = quad*4 + v  [m89/m91]
                int grow = bm * 128 + wm * 64 + mt * 16 + quad * 4 + v;
                int gcol = bn * 128 + wn * 64 + nt * 16 + row;
                C[(size_t)grow * N + gcol] = (OUT)val;
            }
        }
    }
}

// ---------------------------------------------------------------------------
// RoPE + reorder: qkv[token][6144] -> Q[b][32][l][128] (roped),
// K[b][8][l][128] (roped), VT[b][8][128][l] (transposed copy).
// ---------------------------------------------------------------------------
__global__ __launch_bounds__(256)
void rope_reorder(const bf16* __restrict__ qkv, bf16* __restrict__ Q,
                  bf16* __restrict__ Kd, bf16* __restrict__ VT) {
    const int token = blockIdx.y;                          // 0..4095
    const int slot  = blockIdx.x * 4 + (threadIdx.x >> 6); // 0..47
    const int lane  = threadIdx.x & 63;
    const int b = token >> 11, l = token & 2047;
    const bf16* src = qkv + (size_t)token * 6144 + slot * 128;
    if (slot < 40) {
        float x1 = __bfloat162float(src[lane]);
        float x2 = __bfloat162float(src[lane + 64]);
        float inv_freq = powf(500000.0f, -(float)lane * (1.0f / 64.0f));
        float ang = (float)l * inv_freq;
        float s, c;
        sincosf(ang, &s, &c);
        float o1 = x1 * c - x2 * s;
        float o2 = x2 * c + x1 * s;
        bf16* dst;
        if (slot < 32) dst = Q  + ((size_t)(b * 32 + slot)        * 2048 + l) * 128;
        else           dst = Kd + ((size_t)(b * 8  + (slot - 32)) * 2048 + l) * 128;
        dst[lane]      = (bf16)o1;
        dst[lane + 64] = (bf16)o2;
    } else {
        bf16* dst = VT + (size_t)(b * 8 + (slot - 40)) * 128 * 2048 + l;
        dst[(size_t)lane * 2048]        = src[lane];
        dst[(size_t)(lane + 64) * 2048] = src[lane + 64];
    }
}

// ---------------------------------------------------------------------------
// Flash attention, causal, GQA 4:1. Q-tile 64, K-tile 64, 4 waves (16 q rows
// each). REWRITE (round 1): no K/V/Q LDS staging — K/V panels are 512 KB per
// (b,kv-head), L2-resident and reused by 128 blocks, so MFMA fragments are
// read directly from global (guide Common-mistake #7). sP is wave-private
// (each wave touches only its own 16 rows) so ZERO __syncthreads remain.
// LDS 62.5KB -> 9KB; launch_bounds(256,4) -> 4 waves/SIMD (2x occupancy).
// ---------------------------------------------------------------------------
#define SP_STR 72

__global__ __launch_bounds__(256, 4)
void attn_kernel(const bf16* __restrict__ Q, const bf16* __restrict__ K,
                 const bf16* __restrict__ V, bf16* __restrict__ Oout) {
    const int qt = blockIdx.x;          // 0..31 (q-tile of 64 rows)
    const int bh = blockIdx.y;          // 0..63
    const int b = bh >> 5, h = bh & 31;
    const int kh = h >> 2;              // GQA: head h uses kv-head h/4
    const bf16* Qp = Q + ((size_t)(b * 32 + h) * 2048 + qt * 64) * 128;
    const bf16* Kp = K + (size_t)(b * 8 + kh) * 2048 * 128;
    const bf16* Vp = V + (size_t)(b * 8 + kh) * 128 * 2048;   // [d][l]

    __shared__ __align__(16) bf16 sP[4 * 16 * SP_STR];        // wave-private rows

    const int tid = threadIdx.x, lane = tid & 63, wave = tid >> 6;
    const int row = lane & 15, quad = lane >> 4;

    // Q fragments straight to registers (this wave's 16 q-rows), read once.
    // A-frag layout: A[m=lane&15][k=quad*8+j], k-tiles kk*32.
    bf16x8 aq[4];
    #pragma unroll
    for (int kk = 0; kk < 4; kk++)
        aq[kk] = *(const bf16x8*)(Qp + (size_t)(wave * 16 + row) * 128 + (kk * 4 + quad) * 8);

    float pm[4], pl[4];
    f32x4 o_acc[8] = {};
    #pragma unroll
    for (int v = 0; v < 4; v++) { pm[v] = -1e30f; pl[v] = 0.0f; }
    const float scale = 0.08838834764831845f;   // 1/sqrt(128)

    for (int jj = 0; jj <= qt; jj++) {
        const bf16* Kt = Kp + (size_t)jj * 64 * 128;

        // S = Q K^T, B-frags direct from global (L2-resident K panel).
        f32x4 s_acc[4] = {};
        __builtin_amdgcn_s_setprio(1);
        #pragma unroll
        for (int nt = 0; nt < 4; nt++) {
            #pragma unroll
            for (int kk = 0; kk < 4; kk++) {
                bf16x8 bk = *(const bf16x8*)(Kt + (size_t)(nt * 16 + row) * 128 + (kk * 4 + quad) * 8);
                s_acc[nt] = __builtin_amdgcn_mfma_f32_16x16x32_bf16(
                    aq[kk], bk, s_acc[nt], 0, 0, 0);
            }
        }
        __builtin_amdgcn_s_setprio(0);

        // scale + causal mask (diagonal tile only)
        #pragma unroll
        for (int nt = 0; nt < 4; nt++) {
            #pragma unroll
            for (int v = 0; v < 4; v++) {
                float s = s_acc[nt][v] * scale;
                if (jj == qt) {
                    int kpos = nt * 16 + row;
                    int qrow = wave * 16 + quad * 4 + v;
                    if (kpos > qrow) s = -1e30f;
                }
                s_acc[nt][v] = s;
            }
        }
        // online softmax
        float mx[4];
        #pragma unroll
        for (int v = 0; v < 4; v++)
            mx[v] = fmaxf(fmaxf(s_acc[0][v], s_acc[1][v]),
                          fmaxf(s_acc[2][v], s_acc[3][v]));
        #pragma unroll
        for (int off = 1; off < 16; off <<= 1)
            #pragma unroll
            for (int v = 0; v < 4; v++)
                mx[v] = fmaxf(mx[v], __shfl_xor(mx[v], off, 64));
        float mn[4], al[4], rs[4] = {0, 0, 0, 0};
        #pragma unroll
        for (int v = 0; v < 4; v++) {
            mn[v] = fmaxf(pm[v], mx[v]);
            al[v] = __expf(pm[v] - mn[v]);
            pm[v] = mn[v];
        }
        // P = exp(S-m): C-layout -> A-layout via wave-private LDS rows.
        // (intra-wave LDS dep only; compiler's lgkmcnt handles it, no barrier)
        #pragma unroll
        for (int nt = 0; nt < 4; nt++) {
            #pragma unroll
            for (int v = 0; v < 4; v++) {
                float p = __expf(s_acc[nt][v] - mn[v]);
                rs[v] += p;
                int rr = quad * 4 + v;
                int c  = nt * 16 + row;
                sP[(wave * 16 + rr) * SP_STR + c] = (bf16)p;
            }
        }
        #pragma unroll
        for (int off = 1; off < 16; off <<= 1)
            #pragma unroll
            for (int v = 0; v < 4; v++)
                rs[v] += __shfl_xor(rs[v], off, 64);
        #pragma unroll
        for (int v = 0; v < 4; v++) pl[v] = pl[v] * al[v] + rs[v];
        #pragma unroll
        for (int dt = 0; dt < 8; dt++)
            #pragma unroll
            for (int v = 0; v < 4; v++) o_acc[dt][v] *= al[v];

        // O += P V, V frags direct from global [d][l] (L2-resident).
        __builtin_amdgcn_s_setprio(1);
        #pragma unroll
        for (int kk = 0; kk < 2; kk++) {
            bf16x8 pa = *(const bf16x8*)(sP + (wave * 16 + row) * SP_STR + (kk * 4 + quad) * 8);
            #pragma unroll
            for (int dt = 0; dt < 8; dt++) {
                bf16x8 vb = *(const bf16x8*)(Vp + (size_t)(dt * 16 + row) * 2048
                                             + jj * 64 + (kk * 4 + quad) * 8);
                o_acc[dt] = __builtin_amdgcn_mfma_f32_16x16x32_bf16(
                    pa, vb, o_acc[dt], 0, 0, 0);
            }
        }
        __builtin_amdgcn_s_setprio(0);
    }

    // epilogue: O / l, write token-major [token][h*128+d]
    const int token = b * 2048 + qt * 64 + wave * 16;
    #pragma unroll
    for (int dt = 0; dt < 8; dt++) {
        #pragma unroll
        for (int v = 0; v < 4; v++) {
            float o = o_acc[dt][v] / pl[v];
            int trow = token + quad * 4 + v;
            Oout[(size_t)trow * 4096 + h * 128 + dt * 16 + row] = (bf16)o;
        }
    }
}

// ---------------------------------------------------------------------------
// Workspace plan (peak 128 MB; all regions fully rewritten each call):
//   0..32   xb (x as bf16)   -> later overwritten by attn output
//   32..80  Wqkvb            -> after GEMM1: Qb(32..64) Kb(64..72) VTb(72..80)
//   80..128 qkv              -> after rope:  Woutb(80..112)
// d_out is FLOAT32 (reference output dtype) — 64 MB.
// ---------------------------------------------------------------------------
extern "C" void kernel_launch(void* const* d_in, const int* in_sizes, int n_in,
                              void* d_out, int out_size, void* d_ws, size_t ws_size,
                              hipStream_t stream) {
    float* out = (float*)d_out;                // (2,2048,4096) float32

    const size_t MB = 1024 * 1024;
    char* ws = (char*)d_ws;
    bf16* xb    = (bf16*)(ws);                 // 0..32 MB
    bf16* Wqkvb = (bf16*)(ws + 32 * MB);       // 32..80 MB
    bf16* qkv   = (bf16*)(ws + 80 * MB);       // 80..128 MB
    bf16* Qb    = (bf16*)(ws + 32 * MB);       // over dead Wqkvb
    bf16* Kb    = (bf16*)(ws + 64 * MB);
    bf16* VTb   = (bf16*)(ws + 72 * MB);
    bf16* Woutb = (bf16*)(ws + 80 * MB);       // over dead qkv
    bf16* attn  = xb;                          // over dead xb

    convert_to_bf16<<<8192,  256, 0, stream>>>(d_in[0], xb,    16777216L);
    convert_to_bf16<<<12288, 256, 0, stream>>>(d_in[1], Wqkvb, 25165824L);
    // 1) qkv = clip(x @ Wqkv^T, +-8)   (bf16 out)
    gemm_bt<true, bf16><<<dim3(48, 32), 256, 0, stream>>>(xb, Wqkvb, qkv, 4096, 6144, 4096);
    // 2) rope + reorder (reads 80..128, writes 32..80)
    rope_reorder<<<dim3(12, 4096), 256, 0, stream>>>(qkv, Qb, Kb, VTb);
    // (qkv now dead; stage Wout there)
    convert_to_bf16<<<8192,  256, 0, stream>>>(d_in[2], Woutb, 16777216L);
    // 3) causal GQA flash attention -> attn[token][4096] (reads 32..80, writes 0..32)
    attn_kernel<<<dim3(32, 64), 256, 0, stream>>>(Qb, Kb, VTb, attn);
    // 4) out = attn @ Wout^T            (FLOAT out -> d_out)
    gemm_bt<false, float><<<dim3(32, 32), 256, 0, stream>>>(attn, Woutb, out, 4096, 4096, 4096);
}

// Round 2
// 1035.883 us; speedup vs baseline: 1.5859x; 1.5859x over previous
//
#include <hip/hip_runtime.h>
#include <hip/hip_bf16.h>
#include <math.h>

typedef __hip_bfloat16 bf16;
typedef __attribute__((ext_vector_type(8))) short bf16x8;   // 8 bf16 = 4 VGPRs (MFMA A/B frag)
typedef __attribute__((ext_vector_type(4))) float f32x4;    // MFMA C/D frag

__device__ __forceinline__ void glds16(const bf16* g, bf16* l) {
    __builtin_amdgcn_global_load_lds(
        (const __attribute__((address_space(1))) void*)g,
        (__attribute__((address_space(3))) void*)l, 16, 0, 0);
}

// ---------------------------------------------------------------------------
// Self-detecting convert: each wave inspects the tensor's first 128 ushorts.
// True bf16 N(0,1): no exponent >= 0x86 (|x|>=128). fp32 reinterpreted: even
// ushorts are low-mantissa halves, ~47% have exp>=0x86. Wave-uniform branch.
// ---------------------------------------------------------------------------
__global__ __launch_bounds__(256)
void convert_to_bf16(const void* __restrict__ src, bf16* __restrict__ dst, long n) {
    const unsigned short* u16 = (const unsigned short*)src;
    int lane = threadIdx.x & 63;
    unsigned short u = u16[lane * 2];
    int e = (u >> 7) & 0xFF;
    int isf32 = __popcll(__ballot(e >= 0x86)) > 4;   // wave-uniform
    long i = ((long)blockIdx.x * 256 + threadIdx.x) * 8;
    if (i >= n) return;
    if (isf32) {
        const float* s = (const float*)src;
        bf16x8 o;
        #pragma unroll
        for (int j = 0; j < 8; j++) {
            bf16 b = (bf16)s[i + j];
            o[j] = *(short*)&b;
        }
        *(bf16x8*)(dst + i) = o;
    } else {
        *(bf16x8*)(dst + i) = *(const bf16x8*)((const bf16*)src + i);
    }
}

// ---------------------------------------------------------------------------
// GEMM: C[M][N] = clip?(A[M][K] @ B[N][K]^T). bf16 in, fp32 accum, OUT out.
// m97 structure: 128x128 tile, BK=32, global_load_lds width=16, 4 waves 2x2.
// ---------------------------------------------------------------------------
template<bool CLIP, typename OUT>
__global__ __launch_bounds__(256)
void gemm_bt(const bf16* __restrict__ A, const bf16* __restrict__ B,
             OUT* __restrict__ C, int M, int N, int K) {
    __shared__ __align__(16) bf16 sA[128 * 32];
    __shared__ __align__(16) bf16 sB[128 * 32];
    const int tid  = threadIdx.x;
    const int lane = tid & 63;
    const int wave = tid >> 6;
    const int wm   = wave >> 1;
    const int wn   = wave & 1;
    const int row  = lane & 15;
    const int quad = lane >> 4;
    const int bn = blockIdx.x, bm = blockIdx.y;

    const int r  = tid >> 2;            // 0..63
    const int kc = (tid & 3) * 8;       // 0,8,16,24
    const bf16* gA = A + (size_t)(bm * 128 + r) * K + kc;
    const bf16* gB = B + (size_t)(bn * 128 + r) * K + kc;
    bf16* lA = sA + tid * 8;            // contiguous in tid => glds-compatible
    bf16* lB = sB + tid * 8;

    f32x4 acc[4][4] = {};

    for (int kt = 0; kt < K; kt += 32) {
        glds16(gA + kt,                    lA);
        glds16(gA + kt + (size_t)64 * K,   lA + 2048);
        glds16(gB + kt,                    lB);
        glds16(gB + kt + (size_t)64 * K,   lB + 2048);
        __syncthreads();
        bf16x8 af[4], bfr[4];
        #pragma unroll
        for (int mt = 0; mt < 4; mt++)
            af[mt] = *(const bf16x8*)(sA + (wm * 64 + mt * 16 + row) * 32 + quad * 8);
        #pragma unroll
        for (int nt = 0; nt < 4; nt++)
            bfr[nt] = *(const bf16x8*)(sB + (wn * 64 + nt * 16 + row) * 32 + quad * 8);
        #pragma unroll
        for (int mt = 0; mt < 4; mt++)
            #pragma unroll
            for (int nt = 0; nt < 4; nt++)
                acc[mt][nt] = __builtin_amdgcn_mfma_f32_16x16x32_bf16(
                    af[mt], bfr[nt], acc[mt][nt], 0, 0, 0);
        __syncthreads();
    }

    #pragma unroll
    for (int mt = 0; mt < 4; mt++) {
        #pragma unroll
        for (int nt = 0; nt < 4; nt++) {
            #pragma unroll
            for (int v = 0; v < 4; v++) {
                float val = acc[mt][nt][v];
                if (CLIP) val = fminf(fmaxf(val, -8.0f), 8.0f);
                // C/D layout: col = lane&15, row = quad*4 + v  [m89/m91]
                int grow = bm * 128 + wm * 64 + mt * 16 + quad * 4 + v;
                int gcol = bn * 128 + wn * 64 + nt * 16 + row;
                C[(size_t)grow * N + gcol] = (OUT)val;
            }
        }
    }
}

// ---------------------------------------------------------------------------
// RoPE + reorder: qkv[token][6144] -> Q[b][32][l][128] (roped),
// K[b][8][l][128] (roped), VT[b][8][128][l] (transposed copy).
// ---------------------------------------------------------------------------
__global__ __launch_bounds__(256)
void rope_reorder(const bf16* __restrict__ qkv, bf16* __restrict__ Q,
                  bf16* __restrict__ Kd, bf16* __restrict__ VT) {
    const int token = blockIdx.y;                          // 0..4095
    const int slot  = blockIdx.x * 4 + (threadIdx.x >> 6); // 0..47
    const int lane  = threadIdx.x & 63;
    const int b = token >> 11, l = token & 2047;
    const bf16* src = qkv + (size_t)token * 6144 + slot * 128;
    if (slot < 40) {
        float x1 = __bfloat162float(src[lane]);
        float x2 = __bfloat162float(src[lane + 64]);
        float inv_freq = powf(500000.0f, -(float)lane * (1.0f / 64.0f));
        float ang = (float)l * inv_freq;
        float s, c;
        sincosf(ang, &s, &c);
        float o1 = x1 * c - x2 * s;
        float o2 = x2 * c + x1 * s;
        bf16* dst;
        if (slot < 32) dst = Q  + ((size_t)(b * 32 + slot)        * 2048 + l) * 128;
        else           dst = Kd + ((size_t)(b * 8  + (slot - 32)) * 2048 + l) * 128;
        dst[lane]      = (bf16)o1;
        dst[lane + 64] = (bf16)o2;
    } else {
        bf16* dst = VT + (size_t)(b * 8 + (slot - 40)) * 128 * 2048 + l;
        dst[(size_t)lane * 2048]        = src[lane];
        dst[(size_t)(lane + 64) * 2048] = src[lane + 64];
    }
}

// ---------------------------------------------------------------------------
// Flash attention, causal, GQA 4:1. Round 2: LDS staging RESTORED (round 1
// proved direct-from-global fragment reads are latency-poison), with three
// fixes over round 0:
//   1. T14 async-stage: next K/V tile's global loads issue into registers
//      BEFORE compute; barrier -> ds_write -> barrier after. Latency hides
//      under QK^T+softmax+PV.
//   2. XOR-swizzle (byte ^= (row&7)<<4) on sK/sV instead of padded strides.
//      Balanced: every wave64 b128 read = 8 dwords/bank = LDS minimum.
//   3. No sQ (Q frags in regs, proven round 1). LDS 62.5 -> 41 KB -> 3
//      blocks/CU (launch_bounds(256,3)).
// ---------------------------------------------------------------------------
#define SP_STR 72

__global__ __launch_bounds__(256, 3)
void attn_kernel(const bf16* __restrict__ Q, const bf16* __restrict__ K,
                 const bf16* __restrict__ V, bf16* __restrict__ Oout) {
    const int qt = blockIdx.x;          // 0..31 (q-tile of 64 rows)
    const int bh = blockIdx.y;          // 0..63
    const int b = bh >> 5, h = bh & 31;
    const int kh = h >> 2;              // GQA: head h uses kv-head h/4
    const bf16* Qp = Q + ((size_t)(b * 32 + h) * 2048 + qt * 64) * 128;
    const bf16* Kp = K + (size_t)(b * 8 + kh) * 2048 * 128;
    const bf16* Vp = V + (size_t)(b * 8 + kh) * 128 * 2048;   // [d][l]

    __shared__ __align__(16) bf16 sK[64 * 128];   // 16 KB, XOR-swizzled rows
    __shared__ __align__(16) bf16 sV[128 * 64];   // 16 KB, XOR-swizzled rows
    __shared__ __align__(16) bf16 sP[4 * 16 * SP_STR];   // wave-private rows

    const int tid = threadIdx.x, lane = tid & 63, wave = tid >> 6;
    const int row = lane & 15, quad = lane >> 4;

    // staging geometry: 64B/thread per tile, contiguous-per-instruction.
    const int kr  = tid >> 2;            // K row 0..63 (256B rows)
    const int kce = (tid & 3) * 8;       // elem base; chunks at +j*32
    const int vr  = tid >> 1;            // V row 0..127 (128B rows)
    const int vce = (tid & 1) * 8;       // elem base; chunks at +j*16
    const int kxor = (kr & 7) << 4;
    const int vxor = (vr & 7) << 4;
    const int rx   = (row & 7) << 4;     // read-side XOR (K and V rows: &7 == row&7)
    char* sKb = (char*)sK;
    char* sVb = (char*)sV;

    // Q fragments straight to registers (this wave's 16 q-rows), read once.
    bf16x8 aq[4];
    #pragma unroll
    for (int kk = 0; kk < 4; kk++)
        aq[kk] = *(const bf16x8*)(Qp + (size_t)(wave * 16 + row) * 128 + (kk * 4 + quad) * 8);

    // prologue: stage tile 0
    bf16x8 kpf[4], vpf[4];
    #pragma unroll
    for (int j = 0; j < 4; j++) {
        kpf[j] = *(const bf16x8*)(Kp + (size_t)kr * 128 + kce + j * 32);
        vpf[j] = *(const bf16x8*)(Vp + (size_t)vr * 2048 + vce + j * 16);
    }
    #pragma unroll
    for (int j = 0; j < 4; j++) {
        *(bf16x8*)(sKb + kr * 256 + (((kce + j * 32) * 2) ^ kxor)) = kpf[j];
        *(bf16x8*)(sVb + vr * 128 + (((vce + j * 16) * 2) ^ vxor)) = vpf[j];
    }
    __syncthreads();

    float pm[4], pl[4];
    f32x4 o_acc[8] = {};
    #pragma unroll
    for (int v = 0; v < 4; v++) { pm[v] = -1e30f; pl[v] = 0.0f; }
    const float scale = 0.08838834764831845f;   // 1/sqrt(128)

    for (int jj = 0; jj <= qt; jj++) {
        // T14: issue next tile's loads EARLY (results used only after barrier)
        if (jj < qt) {
            const bf16* Kn = Kp + (size_t)(jj + 1) * 64 * 128;
            #pragma unroll
            for (int j = 0; j < 4; j++) {
                kpf[j] = *(const bf16x8*)(Kn + (size_t)kr * 128 + kce + j * 32);
                vpf[j] = *(const bf16x8*)(Vp + (size_t)vr * 2048 + (jj + 1) * 64 + vce + j * 16);
            }
        }

        // S = Q K^T. B-frags from swizzled sK.
        f32x4 s_acc[4] = {};
        __builtin_amdgcn_s_setprio(1);
        #pragma unroll
        for (int nt = 0; nt < 4; nt++) {
            #pragma unroll
            for (int kk = 0; kk < 4; kk++) {
                bf16x8 bk = *(const bf16x8*)(sKb + (nt * 16 + row) * 256
                                             + (((kk * 4 + quad) * 16) ^ rx));
                s_acc[nt] = __builtin_amdgcn_mfma_f32_16x16x32_bf16(
                    aq[kk], bk, s_acc[nt], 0, 0, 0);
            }
        }
        __builtin_amdgcn_s_setprio(0);

        // scale + causal mask (diagonal tile only)
        #pragma unroll
        for (int nt = 0; nt < 4; nt++) {
            #pragma unroll
            for (int v = 0; v < 4; v++) {
                float s = s_acc[nt][v] * scale;
                if (jj == qt) {
                    int kpos = nt * 16 + row;
                    int qrow = wave * 16 + quad * 4 + v;
                    if (kpos > qrow) s = -1e30f;
                }
                s_acc[nt][v] = s;
            }
        }
        // online softmax
        float mx[4];
        #pragma unroll
        for (int v = 0; v < 4; v++)
            mx[v] = fmaxf(fmaxf(s_acc[0][v], s_acc[1][v]),
                          fmaxf(s_acc[2][v], s_acc[3][v]));
        #pragma unroll
        for (int off = 1; off < 16; off <<= 1)
            #pragma unroll
            for (int v = 0; v < 4; v++)
                mx[v] = fmaxf(mx[v], __shfl_xor(mx[v], off, 64));
        float mn[4], al[4], rs[4] = {0, 0, 0, 0};
        #pragma unroll
        for (int v = 0; v < 4; v++) {
            mn[v] = fmaxf(pm[v], mx[v]);
            al[v] = __expf(pm[v] - mn[v]);
            pm[v] = mn[v];
        }
        // P = exp(S-m): C-layout -> A-layout via wave-private LDS rows.
        #pragma unroll
        for (int nt = 0; nt < 4; nt++) {
            #pragma unroll
            for (int v = 0; v < 4; v++) {
                float p = __expf(s_acc[nt][v] - mn[v]);
                rs[v] += p;
                int rr = quad * 4 + v;
                int c  = nt * 16 + row;
                sP[(wave * 16 + rr) * SP_STR + c] = (bf16)p;
            }
        }
        #pragma unroll
        for (int off = 1; off < 16; off <<= 1)
            #pragma unroll
            for (int v = 0; v < 4; v++)
                rs[v] += __shfl_xor(rs[v], off, 64);
        #pragma unroll
        for (int v = 0; v < 4; v++) pl[v] = pl[v] * al[v] + rs[v];
        #pragma unroll
        for (int dt = 0; dt < 8; dt++)
            #pragma unroll
            for (int v = 0; v < 4; v++) o_acc[dt][v] *= al[v];

        // O += P V, V frags from swizzled sV.
        __builtin_amdgcn_s_setprio(1);
        #pragma unroll
        for (int kk = 0; kk < 2; kk++) {
            bf16x8 pa = *(const bf16x8*)(sP + (wave * 16 + row) * SP_STR + (kk * 4 + quad) * 8);
            #pragma unroll
            for (int dt = 0; dt < 8; dt++) {
                bf16x8 vb = *(const bf16x8*)(sVb + (dt * 16 + row) * 128
                                             + (((kk * 4 + quad) * 16) ^ rx));
                o_acc[dt] = __builtin_amdgcn_mfma_f32_16x16x32_bf16(
                    pa, vb, o_acc[dt], 0, 0, 0);
            }
        }
        __builtin_amdgcn_s_setprio(0);

        // T14 write-late: drain prefetched regs into LDS for next iter.
        if (jj < qt) {
            __syncthreads();    // all waves done reading sK/sV of tile jj
            #pragma unroll
            for (int j = 0; j < 4; j++) {
                *(bf16x8*)(sKb + kr * 256 + (((kce + j * 32) * 2) ^ kxor)) = kpf[j];
                *(bf16x8*)(sVb + vr * 128 + (((vce + j * 16) * 2) ^ vxor)) = vpf[j];
            }
            __syncthreads();    // tile jj+1 visible
        }
    }

    // epilogue: O / l, write token-major [token][h*128+d]
    const int token = b * 2048 + qt * 64 + wave * 16;
    #pragma unroll
    for (int dt = 0; dt < 8; dt++) {
        #pragma unroll
        for (int v = 0; v < 4; v++) {
            float o = o_acc[dt][v] / pl[v];
            int trow = token + quad * 4 + v;
            Oout[(size_t)trow * 4096 + h * 128 + dt * 16 + row] = (bf16)o;
        }
    }
}

// ---------------------------------------------------------------------------
// Workspace plan (peak 128 MB; all regions fully rewritten each call):
//   0..32   xb (x as bf16)   -> later overwritten by attn output
//   32..80  Wqkvb            -> after GEMM1: Qb(32..64) Kb(64..72) VTb(72..80)
//   80..128 qkv              -> after rope:  Woutb(80..112)
// d_out is FLOAT32 (reference output dtype) — 64 MB.
// ---------------------------------------------------------------------------
extern "C" void kernel_launch(void* const* d_in, const int* in_sizes, int n_in,
                              void* d_out, int out_size, void* d_ws, size_t ws_size,
                              hipStream_t stream) {
    float* out = (float*)d_out;                // (2,2048,4096) float32

    const size_t MB = 1024 * 1024;
    char* ws = (char*)d_ws;
    bf16* xb    = (bf16*)(ws);                 // 0..32 MB
    bf16* Wqkvb = (bf16*)(ws + 32 * MB);       // 32..80 MB
    bf16* qkv   = (bf16*)(ws + 80 * MB);       // 80..128 MB
    bf16* Qb    = (bf16*)(ws + 32 * MB);       // over dead Wqkvb
    bf16* Kb    = (bf16*)(ws + 64 * MB);
    bf16* VTb   = (bf16*)(ws + 72 * MB);
    bf16* Woutb = (bf16*)(ws + 80 * MB);       // over dead qkv
    bf16* attn  = xb;                          // over dead xb

    convert_to_bf16<<<8192,  256, 0, stream>>>(d_in[0], xb,    16777216L);
    convert_to_bf16<<<12288, 256, 0, stream>>>(d_in[1], Wqkvb, 25165824L);
    // 1) qkv = clip(x @ Wqkv^T, +-8)   (bf16 out)
    gemm_bt<true, bf16><<<dim3(48, 32), 256, 0, stream>>>(xb, Wqkvb, qkv, 4096, 6144, 4096);
    // 2) rope + reorder (reads 80..128, writes 32..80)
    rope_reorder<<<dim3(12, 4096), 256, 0, stream>>>(qkv, Qb, Kb, VTb);
    // (qkv now dead; stage Wout there)
    convert_to_bf16<<<8192,  256, 0, stream>>>(d_in[2], Woutb, 16777216L);
    // 3) causal GQA flash attention -> attn[token][4096] (reads 32..80, writes 0..32)
    attn_kernel<<<dim3(32, 64), 256, 0, stream>>>(Qb, Kb, VTb, attn);
    // 4) out = attn @ Wout^T            (FLOAT out -> d_out)
    gemm_bt<false, float><<<dim3(32, 32), 256, 0, stream>>>(attn, Woutb, out, 4096, 4096, 4096);
}

// Round 3
// 1022.847 us; speedup vs baseline: 1.6061x; 1.0127x over previous
//
#include <hip/hip_runtime.h>
#include <hip/hip_bf16.h>
#include <math.h>

typedef __hip_bfloat16 bf16;
typedef __attribute__((ext_vector_type(8))) short bf16x8;   // 8 bf16 = 4 VGPRs (MFMA A/B frag)
typedef __attribute__((ext_vector_type(4))) float f32x4;    // MFMA C/D frag

__device__ __forceinline__ void glds16(const bf16* g, bf16* l) {
    __builtin_amdgcn_global_load_lds(
        (const __attribute__((address_space(1))) void*)g,
        (__attribute__((address_space(3))) void*)l, 16, 0, 0);
}

// ---------------------------------------------------------------------------
// Self-detecting convert: each wave inspects the tensor's first 128 ushorts.
// True bf16 N(0,1): no exponent >= 0x86 (|x|>=128). fp32 reinterpreted: even
// ushorts are low-mantissa halves, ~47% have exp>=0x86. Wave-uniform branch.
// ---------------------------------------------------------------------------
__global__ __launch_bounds__(256)
void convert_to_bf16(const void* __restrict__ src, bf16* __restrict__ dst, long n) {
    const unsigned short* u16 = (const unsigned short*)src;
    int lane = threadIdx.x & 63;
    unsigned short u = u16[lane * 2];
    int e = (u >> 7) & 0xFF;
    int isf32 = __popcll(__ballot(e >= 0x86)) > 4;   // wave-uniform
    long i = ((long)blockIdx.x * 256 + threadIdx.x) * 8;
    if (i >= n) return;
    if (isf32) {
        const float* s = (const float*)src;
        bf16x8 o;
        #pragma unroll
        for (int j = 0; j < 8; j++) {
            bf16 b = (bf16)s[i + j];
            o[j] = *(short*)&b;
        }
        *(bf16x8*)(dst + i) = o;
    } else {
        *(bf16x8*)(dst + i) = *(const bf16x8*)((const bf16*)src + i);
    }
}

// ---------------------------------------------------------------------------
// GEMM: C[M][N] = clip?(A[M][K] @ B[N][K]^T). bf16 in, fp32 accum, OUT out.
// m97 structure: 128x128 tile, BK=32, global_load_lds width=16, 4 waves 2x2.
// ---------------------------------------------------------------------------
template<bool CLIP, typename OUT>
__global__ __launch_bounds__(256)
void gemm_bt(const bf16* __restrict__ A, const bf16* __restrict__ B,
             OUT* __restrict__ C, int M, int N, int K) {
    __shared__ __align__(16) bf16 sA[128 * 32];
    __shared__ __align__(16) bf16 sB[128 * 32];
    const int tid  = threadIdx.x;
    const int lane = tid & 63;
    const int wave = tid >> 6;
    const int wm   = wave >> 1;
    const int wn   = wave & 1;
    const int row  = lane & 15;
    const int quad = lane >> 4;
    const int bn = blockIdx.x, bm = blockIdx.y;

    const int r  = tid >> 2;            // 0..63
    const int kc = (tid & 3) * 8;       // 0,8,16,24
    const bf16* gA = A + (size_t)(bm * 128 + r) * K + kc;
    const bf16* gB = B + (size_t)(bn * 128 + r) * K + kc;
    bf16* lA = sA + tid * 8;            // contiguous in tid => glds-compatible
    bf16* lB = sB + tid * 8;

    f32x4 acc[4][4] = {};

    for (int kt = 0; kt < K; kt += 32) {
        glds16(gA + kt,                    lA);
        glds16(gA + kt + (size_t)64 * K,   lA + 2048);
        glds16(gB + kt,                    lB);
        glds16(gB + kt + (size_t)64 * K,   lB + 2048);
        __syncthreads();
        bf16x8 af[4], bfr[4];
        #pragma unroll
        for (int mt = 0; mt < 4; mt++)
            af[mt] = *(const bf16x8*)(sA + (wm * 64 + mt * 16 + row) * 32 + quad * 8);
        #pragma unroll
        for (int nt = 0; nt < 4; nt++)
            bfr[nt] = *(const bf16x8*)(sB + (wn * 64 + nt * 16 + row) * 32 + quad * 8);
        #pragma unroll
        for (int mt = 0; mt < 4; mt++)
            #pragma unroll
            for (int nt = 0; nt < 4; nt++)
                acc[mt][nt] = __builtin_amdgcn_mfma_f32_16x16x32_bf16(
                    af[mt], bfr[nt], acc[mt][nt], 0, 0, 0);
        __syncthreads();
    }

    #pragma unroll
    for (int mt = 0; mt < 4; mt++) {
        #pragma unroll
        for (int nt = 0; nt < 4; nt++) {
            #pragma unroll
            for (int v = 0; v < 4; v++) {
                float val = acc[mt][nt][v];
                if (CLIP) val = fminf(fmaxf(val, -8.0f), 8.0f);
                // C/D layout: col = lane&15, row = quad*4 + v  [m89/m91]
                int grow = bm * 128 + wm * 64 + mt * 16 + quad * 4 + v;
                int gcol = bn * 128 + wn * 64 + nt * 16 + row;
                C[(size_t)grow * N + gcol] = (OUT)val;
            }
        }
    }
}

// ---------------------------------------------------------------------------
// RoPE + reorder: qkv[token][6144] -> Q[b][32][l][128] (roped),
// K[b][8][l][128] (roped), VT[b][8][128][l] (transposed copy).
// ---------------------------------------------------------------------------
__global__ __launch_bounds__(256)
void rope_reorder(const bf16* __restrict__ qkv, bf16* __restrict__ Q,
                  bf16* __restrict__ Kd, bf16* __restrict__ VT) {
    const int token = blockIdx.y;                          // 0..4095
    const int slot  = blockIdx.x * 4 + (threadIdx.x >> 6); // 0..47
    const int lane  = threadIdx.x & 63;
    const int b = token >> 11, l = token & 2047;
    const bf16* src = qkv + (size_t)token * 6144 + slot * 128;
    if (slot < 40) {
        float x1 = __bfloat162float(src[lane]);
        float x2 = __bfloat162float(src[lane + 64]);
        float inv_freq = powf(500000.0f, -(float)lane * (1.0f / 64.0f));
        float ang = (float)l * inv_freq;
        float s, c;
        sincosf(ang, &s, &c);
        float o1 = x1 * c - x2 * s;
        float o2 = x2 * c + x1 * s;
        bf16* dst;
        if (slot < 32) dst = Q  + ((size_t)(b * 32 + slot)        * 2048 + l) * 128;
        else           dst = Kd + ((size_t)(b * 8  + (slot - 32)) * 2048 + l) * 128;
        dst[lane]      = (bf16)o1;
        dst[lane + 64] = (bf16)o2;
    } else {
        bf16* dst = VT + (size_t)(b * 8 + (slot - 40)) * 128 * 2048 + l;
        dst[(size_t)lane * 2048]        = src[lane];
        dst[(size_t)(lane + 64) * 2048] = src[lane + 64];
    }
}

// ---------------------------------------------------------------------------
// Flash attention, causal, GQA 4:1. Round 3 changes vs round 2:
//   1. LDS staging writes are LINEAR in tid ((j*256+tid)*16 bytes) — provably
//      conflict-free — with the XOR-swizzle moved to the GLOBAL source
//      address (m173 pattern): slot s of row r holds chunk c = s ^ (r&7).
//      Round 2 swizzled the ds_write side and was 2-way write-conflicted
//      (1.84e7 conflict cycles). Read side unchanged (already swizzle-correct).
//   2. LPT scheduling: qt = 31 - blockIdx.x, longest blocks launch first
//      (causal work ∝ qt+1; round-2 time-avg occupancy 15.6% = tail drain).
// Structure otherwise identical: T14 issue-early/write-late reg staging,
// Q frags in registers, sP wave-private, setprio around MFMA, 41KB LDS,
// launch_bounds(256,3).
// ---------------------------------------------------------------------------
#define SP_STR 72

__global__ __launch_bounds__(256, 3)
void attn_kernel(const bf16* __restrict__ Q, const bf16* __restrict__ K,
                 const bf16* __restrict__ V, bf16* __restrict__ Oout) {
    const int qt = 31 - blockIdx.x;     // LPT: big tiles first
    const int bh = blockIdx.y;          // 0..63
    const int b = bh >> 5, h = bh & 31;
    const int kh = h >> 2;              // GQA: head h uses kv-head h/4
    const bf16* Qp = Q + ((size_t)(b * 32 + h) * 2048 + qt * 64) * 128;
    const bf16* Kp = K + (size_t)(b * 8 + kh) * 2048 * 128;
    const bf16* Vp = V + (size_t)(b * 8 + kh) * 128 * 2048;   // [d][l]

    __shared__ __align__(16) bf16 sK[64 * 128];   // 16 KB, rows source-swizzled
    __shared__ __align__(16) bf16 sV[128 * 64];   // 16 KB, rows source-swizzled
    __shared__ __align__(16) bf16 sP[4 * 16 * SP_STR];   // wave-private rows

    const int tid = threadIdx.x, lane = tid & 63, wave = tid >> 6;
    const int row = lane & 15, quad = lane >> 4;
    const int rx  = (row & 7) << 4;      // read-side XOR (byte bits 4..6)
    char* sKb = (char*)sK;
    char* sVb = (char*)sV;

    // Staging geometry (linear LDS dest, pre-swizzled global source):
    // K tile: 64 rows x 16 slots of 16B. pass j: rows j*16+(tid>>4), slot tid&15.
    //   chunk c = slot ^ (row&7); (j*16)&7==0 so c is j-independent.
    const int krow = tid >> 4;                   // 0..15 (row within pass)
    const int kc8  = (tid & 15) ^ (krow & 7);    // global chunk index (x8 elems)
    // V tile: 128 rows x 8 slots of 16B. pass j: rows j*32+(tid>>3), slot tid&7.
    const int vrow = tid >> 3;                   // 0..31
    const int vc8  = (tid & 7) ^ (vrow & 7);
    const int ldst = tid * 16;                   // linear LDS byte base, +j*4096

    // Q fragments straight to registers (this wave's 16 q-rows), read once.
    bf16x8 aq[4];
    #pragma unroll
    for (int kk = 0; kk < 4; kk++)
        aq[kk] = *(const bf16x8*)(Qp + (size_t)(wave * 16 + row) * 128 + (kk * 4 + quad) * 8);

    // prologue: stage tile 0
    bf16x8 kpf[4], vpf[4];
    #pragma unroll
    for (int j = 0; j < 4; j++) {
        kpf[j] = *(const bf16x8*)(Kp + (size_t)(j * 16 + krow) * 128 + kc8 * 8);
        vpf[j] = *(const bf16x8*)(Vp + (size_t)(j * 32 + vrow) * 2048 + vc8 * 8);
    }
    #pragma unroll
    for (int j = 0; j < 4; j++) {
        *(bf16x8*)(sKb + ldst + j * 4096) = kpf[j];
        *(bf16x8*)(sVb + ldst + j * 4096) = vpf[j];
    }
    __syncthreads();

    float pm[4], pl[4];
    f32x4 o_acc[8] = {};
    #pragma unroll
    for (int v = 0; v < 4; v++) { pm[v] = -1e30f; pl[v] = 0.0f; }
    const float scale = 0.08838834764831845f;   // 1/sqrt(128)

    for (int jj = 0; jj <= qt; jj++) {
        // T14: issue next tile's loads EARLY (results used only after barrier)
        if (jj < qt) {
            #pragma unroll
            for (int j = 0; j < 4; j++) {
                kpf[j] = *(const bf16x8*)(Kp + (size_t)((jj + 1) * 64 + j * 16 + krow) * 128 + kc8 * 8);
                vpf[j] = *(const bf16x8*)(Vp + (size_t)(j * 32 + vrow) * 2048 + (jj + 1) * 64 + vc8 * 8);
            }
        }

        // S = Q K^T. B-frags from swizzled sK: chunk (kk*4+quad) of row
        // (nt*16+row) lives at slot (kk*4+quad)^(row&7).
        f32x4 s_acc[4] = {};
        __builtin_amdgcn_s_setprio(1);
        #pragma unroll
        for (int nt = 0; nt < 4; nt++) {
            #pragma unroll
            for (int kk = 0; kk < 4; kk++) {
                bf16x8 bk = *(const bf16x8*)(sKb + (nt * 16 + row) * 256
                                             + (((kk * 4 + quad) * 16) ^ rx));
                s_acc[nt] = __builtin_amdgcn_mfma_f32_16x16x32_bf16(
                    aq[kk], bk, s_acc[nt], 0, 0, 0);
            }
        }
        __builtin_amdgcn_s_setprio(0);

        // scale + causal mask (diagonal tile only)
        #pragma unroll
        for (int nt = 0; nt < 4; nt++) {
            #pragma unroll
            for (int v = 0; v < 4; v++) {
                float s = s_acc[nt][v] * scale;
                if (jj == qt) {
                    int kpos = nt * 16 + row;
                    int qrow = wave * 16 + quad * 4 + v;
                    if (kpos > qrow) s = -1e30f;
                }
                s_acc[nt][v] = s;
            }
        }
        // online softmax
        float mx[4];
        #pragma unroll
        for (int v = 0; v < 4; v++)
            mx[v] = fmaxf(fmaxf(s_acc[0][v], s_acc[1][v]),
                          fmaxf(s_acc[2][v], s_acc[3][v]));
        #pragma unroll
        for (int off = 1; off < 16; off <<= 1)
            #pragma unroll
            for (int v = 0; v < 4; v++)
                mx[v] = fmaxf(mx[v], __shfl_xor(mx[v], off, 64));
        float mn[4], al[4], rs[4] = {0, 0, 0, 0};
        #pragma unroll
        for (int v = 0; v < 4; v++) {
            mn[v] = fmaxf(pm[v], mx[v]);
            al[v] = __expf(pm[v] - mn[v]);
            pm[v] = mn[v];
        }
        // P = exp(S-m): C-layout -> A-layout via wave-private LDS rows.
        #pragma unroll
        for (int nt = 0; nt < 4; nt++) {
            #pragma unroll
            for (int v = 0; v < 4; v++) {
                float p = __expf(s_acc[nt][v] - mn[v]);
                rs[v] += p;
                int rr = quad * 4 + v;
                int c  = nt * 16 + row;
                sP[(wave * 16 + rr) * SP_STR + c] = (bf16)p;
            }
        }
        #pragma unroll
        for (int off = 1; off < 16; off <<= 1)
            #pragma unroll
            for (int v = 0; v < 4; v++)
                rs[v] += __shfl_xor(rs[v], off, 64);
        #pragma unroll
        for (int v = 0; v < 4; v++) pl[v] = pl[v] * al[v] + rs[v];
        #pragma unroll
        for (int dt = 0; dt < 8; dt++)
            #pragma unroll
            for (int v = 0; v < 4; v++) o_acc[dt][v] *= al[v];

        // O += P V, V frags from swizzled sV (row dt*16+row, chunk kk*4+quad).
        __builtin_amdgcn_s_setprio(1);
        #pragma unroll
        for (int kk = 0; kk < 2; kk++) {
            bf16x8 pa = *(const bf16x8*)(sP + (wave * 16 + row) * SP_STR + (kk * 4 + quad) * 8);
            #pragma unroll
            for (int dt = 0; dt < 8; dt++) {
                bf16x8 vb = *(const bf16x8*)(sVb + (dt * 16 + row) * 128
                                             + (((kk * 4 + quad) * 16) ^ rx));
                o_acc[dt] = __builtin_amdgcn_mfma_f32_16x16x32_bf16(
                    pa, vb, o_acc[dt], 0, 0, 0);
            }
        }
        __builtin_amdgcn_s_setprio(0);

        // T14 write-late: drain prefetched regs into LDS (linear, conflict-free)
        if (jj < qt) {
            __syncthreads();    // all waves done reading sK/sV of tile jj
            #pragma unroll
            for (int j = 0; j < 4; j++) {
                *(bf16x8*)(sKb + ldst + j * 4096) = kpf[j];
                *(bf16x8*)(sVb + ldst + j * 4096) = vpf[j];
            }
            __syncthreads();    // tile jj+1 visible
        }
    }

    // epilogue: O / l, write token-major [token][h*128+d]
    const int token = b * 2048 + qt * 64 + wave * 16;
    #pragma unroll
    for (int dt = 0; dt < 8; dt++) {
        #pragma unroll
        for (int v = 0; v < 4; v++) {
            float o = o_acc[dt][v] / pl[v];
            int trow = token + quad * 4 + v;
            Oout[(size_t)trow * 4096 + h * 128 + dt * 16 + row] = (bf16)o;
        }
    }
}

// ---------------------------------------------------------------------------
// Workspace plan (peak 128 MB; all regions fully rewritten each call):
//   0..32   xb (x as bf16)   -> later overwritten by attn output
//   32..80  Wqkvb            -> after GEMM1: Qb(32..64) Kb(64..72) VTb(72..80)
//   80..128 qkv              -> after rope:  Woutb(80..112)
// d_out is FLOAT32 (reference output dtype) — 64 MB.
// ---------------------------------------------------------------------------
extern "C" void kernel_launch(void* const* d_in, const int* in_sizes, int n_in,
                              void* d_out, int out_size, void* d_ws, size_t ws_size,
                              hipStream_t stream) {
    float* out = (float*)d_out;                // (2,2048,4096) float32

    const size_t MB = 1024 * 1024;
    char* ws = (char*)d_ws;
    bf16* xb    = (bf16*)(ws);                 // 0..32 MB
    bf16* Wqkvb = (bf16*)(ws + 32 * MB);       // 32..80 MB
    bf16* qkv   = (bf16*)(ws + 80 * MB);       // 80..128 MB
    bf16* Qb    = (bf16*)(ws + 32 * MB);       // over dead Wqkvb
    bf16* Kb    = (bf16*)(ws + 64 * MB);
    bf16* VTb   = (bf16*)(ws + 72 * MB);
    bf16* Woutb = (bf16*)(ws + 80 * MB);       // over dead qkv
    bf16* attn  = xb;                          // over dead xb

    convert_to_bf16<<<8192,  256, 0, stream>>>(d_in[0], xb,    16777216L);
    convert_to_bf16<<<12288, 256, 0, stream>>>(d_in[1], Wqkvb, 25165824L);
    // 1) qkv = clip(x @ Wqkv^T, +-8)   (bf16 out)
    gemm_bt<true, bf16><<<dim3(48, 32), 256, 0, stream>>>(xb, Wqkvb, qkv, 4096, 6144, 4096);
    // 2) rope + reorder (reads 80..128, writes 32..80)
    rope_reorder<<<dim3(12, 4096), 256, 0, stream>>>(qkv, Qb, Kb, VTb);
    // (qkv now dead; stage Wout there)
    convert_to_bf16<<<8192,  256, 0, stream>>>(d_in[2], Woutb, 16777216L);
    // 3) causal GQA flash attention -> attn[token][4096] (reads 32..80, writes 0..32)
    attn_kernel<<<dim3(32, 64), 256, 0, stream>>>(Qb, Kb, VTb, attn);
    // 4) out = attn @ Wout^T            (FLOAT out -> d_out)
    gemm_bt<false, float><<<dim3(32, 32), 256, 0, stream>>>(attn, Woutb, out, 4096, 4096, 4096);
}

// Round 4
// 948.834 us; speedup vs baseline: 1.7314x; 1.0780x over previous
//
#include <hip/hip_runtime.h>
#include <hip/hip_bf16.h>
#include <math.h>

typedef __hip_bfloat16 bf16;
typedef __attribute__((ext_vector_type(8))) short bf16x8;   // 8 bf16 = 4 VGPRs (MFMA A/B frag)
typedef __attribute__((ext_vector_type(4))) short bf16x4;   // 4 bf16 = 8 bytes
typedef __attribute__((ext_vector_type(4))) float f32x4;    // MFMA C/D frag

__device__ __forceinline__ void glds16(const bf16* g, bf16* l) {
    __builtin_amdgcn_global_load_lds(
        (const __attribute__((address_space(1))) void*)g,
        (__attribute__((address_space(3))) void*)l, 16, 0, 0);
}

// ---------------------------------------------------------------------------
// Self-detecting convert: each wave inspects the tensor's first 128 ushorts.
// ---------------------------------------------------------------------------
__global__ __launch_bounds__(256)
void convert_to_bf16(const void* __restrict__ src, bf16* __restrict__ dst, long n) {
    const unsigned short* u16 = (const unsigned short*)src;
    int lane = threadIdx.x & 63;
    unsigned short u = u16[lane * 2];
    int e = (u >> 7) & 0xFF;
    int isf32 = __popcll(__ballot(e >= 0x86)) > 4;   // wave-uniform
    long i = ((long)blockIdx.x * 256 + threadIdx.x) * 8;
    if (i >= n) return;
    if (isf32) {
        const float* s = (const float*)src;
        bf16x8 o;
        #pragma unroll
        for (int j = 0; j < 8; j++) {
            bf16 b = (bf16)s[i + j];
            o[j] = *(short*)&b;
        }
        *(bf16x8*)(dst + i) = o;
    } else {
        *(bf16x8*)(dst + i) = *(const bf16x8*)((const bf16*)src + i);
    }
}

// ---------------------------------------------------------------------------
// GEMM: C[M][N] = clip?(A[M][K] @ B[N][K]^T). bf16 in, fp32 accum, OUT out.
// m97 structure: 128x128 tile, BK=32, global_load_lds width=16, 4 waves 2x2.
// ---------------------------------------------------------------------------
template<bool CLIP, typename OUT>
__global__ __launch_bounds__(256)
void gemm_bt(const bf16* __restrict__ A, const bf16* __restrict__ B,
             OUT* __restrict__ C, int M, int N, int K) {
    __shared__ __align__(16) bf16 sA[128 * 32];
    __shared__ __align__(16) bf16 sB[128 * 32];
    const int tid  = threadIdx.x;
    const int lane = tid & 63;
    const int wave = tid >> 6;
    const int wm   = wave >> 1;
    const int wn   = wave & 1;
    const int row  = lane & 15;
    const int quad = lane >> 4;
    const int bn = blockIdx.x, bm = blockIdx.y;

    const int r  = tid >> 2;            // 0..63
    const int kc = (tid & 3) * 8;       // 0,8,16,24
    const bf16* gA = A + (size_t)(bm * 128 + r) * K + kc;
    const bf16* gB = B + (size_t)(bn * 128 + r) * K + kc;
    bf16* lA = sA + tid * 8;            // contiguous in tid => glds-compatible
    bf16* lB = sB + tid * 8;

    f32x4 acc[4][4] = {};

    for (int kt = 0; kt < K; kt += 32) {
        glds16(gA + kt,                    lA);
        glds16(gA + kt + (size_t)64 * K,   lA + 2048);
        glds16(gB + kt,                    lB);
        glds16(gB + kt + (size_t)64 * K,   lB + 2048);
        __syncthreads();
        bf16x8 af[4], bfr[4];
        #pragma unroll
        for (int mt = 0; mt < 4; mt++)
            af[mt] = *(const bf16x8*)(sA + (wm * 64 + mt * 16 + row) * 32 + quad * 8);
        #pragma unroll
        for (int nt = 0; nt < 4; nt++)
            bfr[nt] = *(const bf16x8*)(sB + (wn * 64 + nt * 16 + row) * 32 + quad * 8);
        #pragma unroll
        for (int mt = 0; mt < 4; mt++)
            #pragma unroll
            for (int nt = 0; nt < 4; nt++)
                acc[mt][nt] = __builtin_amdgcn_mfma_f32_16x16x32_bf16(
                    af[mt], bfr[nt], acc[mt][nt], 0, 0, 0);
        __syncthreads();
    }

    #pragma unroll
    for (int mt = 0; mt < 4; mt++) {
        #pragma unroll
        for (int nt = 0; nt < 4; nt++) {
            #pragma unroll
            for (int v = 0; v < 4; v++) {
                float val = acc[mt][nt][v];
                if (CLIP) val = fminf(fmaxf(val, -8.0f), 8.0f);
                // C/D layout: col = lane&15, row = quad*4 + v  [m89/m91]
                int grow = bm * 128 + wm * 64 + mt * 16 + quad * 4 + v;
                int gcol = bn * 128 + wn * 64 + nt * 16 + row;
                C[(size_t)grow * N + gcol] = (OUT)val;
            }
        }
    }
}

// ---------------------------------------------------------------------------
// RoPE + reorder: qkv[token][6144] -> Q[b][32][l][128] (roped),
// K[b][8][l][128] (roped), VT[b][8][128][l] (transposed copy).
// ---------------------------------------------------------------------------
__global__ __launch_bounds__(256)
void rope_reorder(const bf16* __restrict__ qkv, bf16* __restrict__ Q,
                  bf16* __restrict__ Kd, bf16* __restrict__ VT) {
    const int token = blockIdx.y;                          // 0..4095
    const int slot  = blockIdx.x * 4 + (threadIdx.x >> 6); // 0..47
    const int lane  = threadIdx.x & 63;
    const int b = token >> 11, l = token & 2047;
    const bf16* src = qkv + (size_t)token * 6144 + slot * 128;
    if (slot < 40) {
        float x1 = __bfloat162float(src[lane]);
        float x2 = __bfloat162float(src[lane + 64]);
        float inv_freq = powf(500000.0f, -(float)lane * (1.0f / 64.0f));
        float ang = (float)l * inv_freq;
        float s, c;
        sincosf(ang, &s, &c);
        float o1 = x1 * c - x2 * s;
        float o2 = x2 * c + x1 * s;
        bf16* dst;
        if (slot < 32) dst = Q  + ((size_t)(b * 32 + slot)        * 2048 + l) * 128;
        else           dst = Kd + ((size_t)(b * 8  + (slot - 32)) * 2048 + l) * 128;
        dst[lane]      = (bf16)o1;
        dst[lane + 64] = (bf16)o2;
    } else {
        bf16* dst = VT + (size_t)(b * 8 + (slot - 40)) * 128 * 2048 + l;
        dst[(size_t)lane * 2048]        = src[lane];
        dst[(size_t)(lane + 64) * 2048] = src[lane + 64];
    }
}

// ---------------------------------------------------------------------------
// Flash attention, causal, GQA 4:1. Round 4: SWAPPED QK^T (T12 structural
// core): compute S^T = mfma(K_frag, Q_frag) so the C/D layout becomes
//   q-row = lane&15 (LANE-LOCAL), k-pos = nt*16 + quad*4 + v.
// Each lane owns its q-row's softmax stats:
//   - row max/sum: in-lane over 16 vals + 2 shfl_xor (16,32)  [was 32 shfls]
//   - P store: 4x ds_write_b64 of packed bf16x4                [was 16 scalar]
//   - o_acc rescale factors fetched with 4 shfls (rows quad*4+v)
//   - T13 defer-max (THR=8): skip rescale when max growth small
// sP contents identical to before (sP[r][c] = P[r][c]) so the PV read path,
// V staging, T14 issue-early/write-late, and epilogue are all unchanged.
// ---------------------------------------------------------------------------
#define SP_STR 72

__global__ __launch_bounds__(256, 3)
void attn_kernel(const bf16* __restrict__ Q, const bf16* __restrict__ K,
                 const bf16* __restrict__ V, bf16* __restrict__ Oout) {
    const int qt = 31 - blockIdx.x;     // LPT: big tiles first
    const int bh = blockIdx.y;          // 0..63
    const int b = bh >> 5, h = bh & 31;
    const int kh = h >> 2;              // GQA: head h uses kv-head h/4
    const bf16* Qp = Q + ((size_t)(b * 32 + h) * 2048 + qt * 64) * 128;
    const bf16* Kp = K + (size_t)(b * 8 + kh) * 2048 * 128;
    const bf16* Vp = V + (size_t)(b * 8 + kh) * 128 * 2048;   // [d][l]

    __shared__ __align__(16) bf16 sK[64 * 128];   // 16 KB, rows source-swizzled
    __shared__ __align__(16) bf16 sV[128 * 64];   // 16 KB, rows source-swizzled
    __shared__ __align__(16) bf16 sP[4 * 16 * SP_STR];   // wave-private rows

    const int tid = threadIdx.x, lane = tid & 63, wave = tid >> 6;
    const int row = lane & 15, quad = lane >> 4;
    const int rx  = (row & 7) << 4;      // read-side XOR (byte bits 4..6)
    char* sKb = (char*)sK;
    char* sVb = (char*)sV;

    // Staging geometry (linear LDS dest, pre-swizzled global source):
    const int krow = tid >> 4;                   // 0..15 (row within pass)
    const int kc8  = (tid & 15) ^ (krow & 7);    // global chunk index (x8 elems)
    const int vrow = tid >> 3;                   // 0..31
    const int vc8  = (tid & 7) ^ (vrow & 7);
    const int ldst = tid * 16;                   // linear LDS byte base, +j*4096

    // Q fragments straight to registers (this wave's 16 q-rows), read once.
    bf16x8 aq[4];
    #pragma unroll
    for (int kk = 0; kk < 4; kk++)
        aq[kk] = *(const bf16x8*)(Qp + (size_t)(wave * 16 + row) * 128 + (kk * 4 + quad) * 8);

    // prologue: stage tile 0
    bf16x8 kpf[4], vpf[4];
    #pragma unroll
    for (int j = 0; j < 4; j++) {
        kpf[j] = *(const bf16x8*)(Kp + (size_t)(j * 16 + krow) * 128 + kc8 * 8);
        vpf[j] = *(const bf16x8*)(Vp + (size_t)(j * 32 + vrow) * 2048 + vc8 * 8);
    }
    #pragma unroll
    for (int j = 0; j < 4; j++) {
        *(bf16x8*)(sKb + ldst + j * 4096) = kpf[j];
        *(bf16x8*)(sVb + ldst + j * 4096) = vpf[j];
    }
    __syncthreads();

    float pm = -1e30f, pl = 0.0f;       // per-lane stats for q-row lane&15
    f32x4 o_acc[8] = {};
    const float scale = 0.08838834764831845f;   // 1/sqrt(128)

    for (int jj = 0; jj <= qt; jj++) {
        // T14: issue next tile's loads EARLY (results used only after barrier)
        if (jj < qt) {
            #pragma unroll
            for (int j = 0; j < 4; j++) {
                kpf[j] = *(const bf16x8*)(Kp + (size_t)((jj + 1) * 64 + j * 16 + krow) * 128 + kc8 * 8);
                vpf[j] = *(const bf16x8*)(Vp + (size_t)(j * 32 + vrow) * 2048 + (jj + 1) * 64 + vc8 * 8);
            }
        }

        // S^T = K Q^T (SWAPPED): A = K rows, B = Q rows.
        // D[m=quad*4+v = k-pos in subtile nt][n=lane&15 = q-row].
        f32x4 s_acc[4] = {};
        __builtin_amdgcn_s_setprio(1);
        #pragma unroll
        for (int nt = 0; nt < 4; nt++) {
            #pragma unroll
            for (int kk = 0; kk < 4; kk++) {
                bf16x8 bk = *(const bf16x8*)(sKb + (nt * 16 + row) * 256
                                             + (((kk * 4 + quad) * 16) ^ rx));
                s_acc[nt] = __builtin_amdgcn_mfma_f32_16x16x32_bf16(
                    bk, aq[kk], s_acc[nt], 0, 0, 0);
            }
        }
        __builtin_amdgcn_s_setprio(0);

        // scale + causal mask (diagonal tile only): kpos = nt*16+quad*4+v,
        // qrow(local) = wave*16 + row.
        #pragma unroll
        for (int nt = 0; nt < 4; nt++) {
            #pragma unroll
            for (int v = 0; v < 4; v++) {
                float s = s_acc[nt][v] * scale;
                if (jj == qt) {
                    int kpos = nt * 16 + quad * 4 + v;
                    int qrow = wave * 16 + row;
                    if (kpos > qrow) s = -1e30f;
                }
                s_acc[nt][v] = s;
            }
        }
        // row max: in-lane over 16 + 2 shfl (across quads)
        float m_loc = s_acc[0][0];
        #pragma unroll
        for (int nt = 0; nt < 4; nt++)
            #pragma unroll
            for (int v = 0; v < 4; v++)
                m_loc = fmaxf(m_loc, s_acc[nt][v]);
        m_loc = fmaxf(m_loc, __shfl_xor(m_loc, 16, 64));
        m_loc = fmaxf(m_loc, __shfl_xor(m_loc, 32, 64));

        // T13 defer-max: only rescale when max grew past THR=8
        if (!__all(m_loc - pm <= 8.0f)) {
            float mn = fmaxf(pm, m_loc);
            float al = __expf(pm - mn);
            pm = mn;
            pl *= al;
            float al_q[4];
            #pragma unroll
            for (int v = 0; v < 4; v++)
                al_q[v] = __shfl(al, quad * 4 + v, 64);
            #pragma unroll
            for (int dt = 0; dt < 8; dt++)
                #pragma unroll
                for (int v = 0; v < 4; v++)
                    o_acc[dt][v] *= al_q[v];
        }

        // P = exp(S - pm), lane-local row: pack 4 bf16, one b64 write per nt.
        float rs = 0.0f;
        #pragma unroll
        for (int nt = 0; nt < 4; nt++) {
            bf16x4 pw;
            #pragma unroll
            for (int v = 0; v < 4; v++) {
                float p = __expf(s_acc[nt][v] - pm);
                rs += p;
                bf16 pb = (bf16)p;
                pw[v] = *(short*)&pb;
            }
            *(bf16x4*)(sP + (wave * 16 + row) * SP_STR + nt * 16 + quad * 4) = pw;
        }
        rs += __shfl_xor(rs, 16, 64);
        rs += __shfl_xor(rs, 32, 64);
        pl += rs;

        // O += P V, pa from sP (sP[r][c] = P[r][c], same as before),
        // vb from swizzled sV.
        __builtin_amdgcn_s_setprio(1);
        #pragma unroll
        for (int kk = 0; kk < 2; kk++) {
            bf16x8 pa = *(const bf16x8*)(sP + (wave * 16 + row) * SP_STR + (kk * 4 + quad) * 8);
            #pragma unroll
            for (int dt = 0; dt < 8; dt++) {
                bf16x8 vb = *(const bf16x8*)(sVb + (dt * 16 + row) * 128
                                             + (((kk * 4 + quad) * 16) ^ rx));
                o_acc[dt] = __builtin_amdgcn_mfma_f32_16x16x32_bf16(
                    pa, vb, o_acc[dt], 0, 0, 0);
            }
        }
        __builtin_amdgcn_s_setprio(0);

        // T14 write-late: drain prefetched regs into LDS (linear, conflict-free)
        if (jj < qt) {
            __syncthreads();    // all waves done reading sK/sV of tile jj
            #pragma unroll
            for (int j = 0; j < 4; j++) {
                *(bf16x8*)(sKb + ldst + j * 4096) = kpf[j];
                *(bf16x8*)(sVb + ldst + j * 4096) = vpf[j];
            }
            __syncthreads();    // tile jj+1 visible
        }
    }

    // epilogue: O / l. o_acc row = quad*4+v -> fetch pl for those rows.
    float pl_q[4];
    #pragma unroll
    for (int v = 0; v < 4; v++)
        pl_q[v] = __shfl(pl, quad * 4 + v, 64);
    const int token = b * 2048 + qt * 64 + wave * 16;
    #pragma unroll
    for (int dt = 0; dt < 8; dt++) {
        #pragma unroll
        for (int v = 0; v < 4; v++) {
            float o = o_acc[dt][v] / pl_q[v];
            int trow = token + quad * 4 + v;
            Oout[(size_t)trow * 4096 + h * 128 + dt * 16 + row] = (bf16)o;
        }
    }
}

// ---------------------------------------------------------------------------
// Workspace plan (peak 128 MB; all regions fully rewritten each call):
//   0..32   xb (x as bf16)   -> later overwritten by attn output
//   32..80  Wqkvb            -> after GEMM1: Qb(32..64) Kb(64..72) VTb(72..80)
//   80..128 qkv              -> after rope:  Woutb(80..112)
// d_out is FLOAT32 (reference output dtype) — 64 MB.
// ---------------------------------------------------------------------------
extern "C" void kernel_launch(void* const* d_in, const int* in_sizes, int n_in,
                              void* d_out, int out_size, void* d_ws, size_t ws_size,
                              hipStream_t stream) {
    float* out = (float*)d_out;                // (2,2048,4096) float32

    const size_t MB = 1024 * 1024;
    char* ws = (char*)d_ws;
    bf16* xb    = (bf16*)(ws);                 // 0..32 MB
    bf16* Wqkvb = (bf16*)(ws + 32 * MB);       // 32..80 MB
    bf16* qkv   = (bf16*)(ws + 80 * MB);       // 80..128 MB
    bf16* Qb    = (bf16*)(ws + 32 * MB);       // over dead Wqkvb
    bf16* Kb    = (bf16*)(ws + 64 * MB);
    bf16* VTb   = (bf16*)(ws + 72 * MB);
    bf16* Woutb = (bf16*)(ws + 80 * MB);       // over dead qkv
    bf16* attn  = xb;                          // over dead xb

    convert_to_bf16<<<8192,  256, 0, stream>>>(d_in[0], xb,    16777216L);
    convert_to_bf16<<<12288, 256, 0, stream>>>(d_in[1], Wqkvb, 25165824L);
    // 1) qkv = clip(x @ Wqkv^T, +-8)   (bf16 out)
    gemm_bt<true, bf16><<<dim3(48, 32), 256, 0, stream>>>(xb, Wqkvb, qkv, 4096, 6144, 4096);
    // 2) rope + reorder (reads 80..128, writes 32..80)
    rope_reorder<<<dim3(12, 4096), 256, 0, stream>>>(qkv, Qb, Kb, VTb);
    // (qkv now dead; stage Wout there)
    convert_to_bf16<<<8192,  256, 0, stream>>>(d_in[2], Woutb, 16777216L);
    // 3) causal GQA flash attention -> attn[token][4096] (reads 32..80, writes 0..32)
    attn_kernel<<<dim3(32, 64), 256, 0, stream>>>(Qb, Kb, VTb, attn);
    // 4) out = attn @ Wout^T            (FLOAT out -> d_out)
    gemm_bt<false, float><<<dim3(32, 32), 256, 0, stream>>>(attn, Woutb, out, 4096, 4096, 4096);
}

// Round 5
// 845.429 us; speedup vs baseline: 1.9431x; 1.1223x over previous
//
#include <hip/hip_runtime.h>
#include <hip/hip_bf16.h>
#include <math.h>

typedef __hip_bfloat16 bf16;
typedef __attribute__((ext_vector_type(8))) short bf16x8;   // 8 bf16 = 4 VGPRs (MFMA A/B frag)
typedef __attribute__((ext_vector_type(4))) short bf16x4;   // 4 bf16 = 8 bytes
typedef __attribute__((ext_vector_type(4))) float f32x4;    // MFMA C/D frag

__device__ __forceinline__ void glds16(const bf16* g, bf16* l) {
    __builtin_amdgcn_global_load_lds(
        (const __attribute__((address_space(1))) void*)g,
        (__attribute__((address_space(3))) void*)l, 16, 0, 0);
}

// ---------------------------------------------------------------------------
// Self-detecting convert: each wave inspects the tensor's first 128 ushorts.
// ---------------------------------------------------------------------------
__global__ __launch_bounds__(256)
void convert_to_bf16(const void* __restrict__ src, bf16* __restrict__ dst, long n) {
    const unsigned short* u16 = (const unsigned short*)src;
    int lane = threadIdx.x & 63;
    unsigned short u = u16[lane * 2];
    int e = (u >> 7) & 0xFF;
    int isf32 = __popcll(__ballot(e >= 0x86)) > 4;   // wave-uniform
    long i = ((long)blockIdx.x * 256 + threadIdx.x) * 8;
    if (i >= n) return;
    if (isf32) {
        const float* s = (const float*)src;
        bf16x8 o;
        #pragma unroll
        for (int j = 0; j < 8; j++) {
            bf16 b = (bf16)s[i + j];
            o[j] = *(short*)&b;
        }
        *(bf16x8*)(dst + i) = o;
    } else {
        *(bf16x8*)(dst + i) = *(const bf16x8*)((const bf16*)src + i);
    }
}

// ---------------------------------------------------------------------------
// GEMM round 5: 256x256 tile, BK=64, 512 threads (8 waves, 2Mx4N), double-
// buffered 128KB LDS, counted-vmcnt pipeline (T4: never drain to 0 in the
// main loop), T2 chunk^row&7 read swizzle (linear glds dest, inverse-swizzled
// global source — rule #21), T5 setprio around MFMA clusters, T1 XCD swizzle.
//
// Sync ledger (per wave, 8 glds instr per K-tile):
//   prologue: stage t0 (8), t1 (8)            -> 16 in flight
//   iter t:   vmcnt(8)  [tile t complete; t+1's 8 in flight]
//             s_barrier [all waves see buf[cur]]
//             ds_read ks0 frags; lgkm0; MFMA ks0
//             ds_read ks1 frags; lgkm0 (reads of buf[cur] done); sched_barrier
//             s_barrier [ALL waves done reading buf[cur]]
//             stage tile t+2 -> buf[cur] (safe now)   -> 16 in flight again
//             MFMA ks1 (register-only)
//   last tile peeled with vmcnt(0), no stage.
// ---------------------------------------------------------------------------
template<bool CLIP, typename OUT>
__global__ __launch_bounds__(512, 2)
void gemm256(const bf16* __restrict__ A, const bf16* __restrict__ B,
             OUT* __restrict__ C, int M, int N, int K) {
    __shared__ __align__(16) bf16 sA[2][256 * 64];
    __shared__ __align__(16) bf16 sB[2][256 * 64];

    const int tid   = threadIdx.x;
    const int lane  = tid & 63;
    const int row16 = lane & 15;
    const int quad  = lane >> 4;
    const int wid   = tid >> 6;
    const int wr    = wid >> 2;          // 0..1  (M half)
    const int wc    = wid & 3;           // 0..3  (N quarter)

    // T1: XCD-aware bijective swizzle (grids here are multiples of 8)
    const int nwg  = gridDim.x * gridDim.y;
    const int orig = blockIdx.y * gridDim.x + blockIdx.x;
    const int cpx  = nwg >> 3;
    const int sw   = (orig & 7) * cpx + (orig >> 3);
    const int bn   = sw % gridDim.x;
    const int bm   = sw / gridDim.x;

    // Staging geometry: issue q covers rows q*64+(tid>>3), slot tid&7 (16B).
    // Linear LDS dest byte = q*8192 + tid*16 = row*128 + slot*16.
    // Source chunk = slot ^ (row&7)  (involution; read applies same XOR).
    const int srow   = tid >> 3;                 // 0..63
    const int schunk = (tid & 7) ^ (srow & 7);
    const bf16* gA = A + (size_t)(bm * 256) * K + schunk * 8;
    const bf16* gB = B + (size_t)(bn * 256) * K + schunk * 8;

    #define STAGE256(u, t)                                                     \
        do {                                                                   \
            _Pragma("unroll")                                                  \
            for (int q = 0; q < 4; q++) {                                      \
                glds16(gA + (size_t)(q * 64 + srow) * K + (t) * 64,            \
                       &sA[u][0] + q * 4096 + tid * 8);                        \
                glds16(gB + (size_t)(q * 64 + srow) * K + (t) * 64,            \
                       &sB[u][0] + q * 4096 + tid * 8);                        \
            }                                                                  \
        } while (0)

    // Fragment read bases (bytes). Row r of a tile lives at r*128; the 16B
    // chunk c of row r sits at slot c^(r&7). cx0/cx1 = swizzled chunk offsets
    // for K-step 0/1 (chunk = ks*4+quad).
    const int cx0 = ((quad) ^ (row16 & 7)) << 4;
    const int cx1 = ((4 + quad) ^ (row16 & 7)) << 4;
    const int aRowOff = (wr * 128 + row16) * 128;
    const int bRowOff = (wc * 64 + row16) * 128;

    f32x4 acc[8][4] = {};

    const int NT = K >> 6;               // 64-wide K-tiles
    STAGE256(0, 0);
    STAGE256(1, 1);

    for (int t = 0; t < NT; t++) {
        const int cur = t & 1;
        if (t + 1 < NT) {
            asm volatile("s_waitcnt vmcnt(8)" ::: "memory");
        } else {
            asm volatile("s_waitcnt vmcnt(0)" ::: "memory");
        }
        __builtin_amdgcn_s_barrier();
        __builtin_amdgcn_sched_barrier(0);

        const char* aRd = (const char*)(&sA[cur][0]) + aRowOff;
        const char* bRd = (const char*)(&sB[cur][0]) + bRowOff;

        // ---- K-step 0 ----
        bf16x8 af0[8], bf0[4];
        #pragma unroll
        for (int i = 0; i < 8; i++)
            af0[i] = *(const bf16x8*)(aRd + i * 2048 + cx0);
        #pragma unroll
        for (int j = 0; j < 4; j++)
            bf0[j] = *(const bf16x8*)(bRd + j * 2048 + cx0);
        asm volatile("s_waitcnt lgkmcnt(0)" ::: "memory");
        __builtin_amdgcn_sched_barrier(0);
        __builtin_amdgcn_s_setprio(1);
        #pragma unroll
        for (int i = 0; i < 8; i++)
            #pragma unroll
            for (int j = 0; j < 4; j++)
                acc[i][j] = __builtin_amdgcn_mfma_f32_16x16x32_bf16(
                    af0[i], bf0[j], acc[i][j], 0, 0, 0);
        __builtin_amdgcn_s_setprio(0);
        __builtin_amdgcn_sched_barrier(0);

        // ---- K-step 1 reads (must complete before buf[cur] is re-staged) ----
        bf16x8 af1[8], bf1[4];
        #pragma unroll
        for (int i = 0; i < 8; i++)
            af1[i] = *(const bf16x8*)(aRd + i * 2048 + cx1);
        #pragma unroll
        for (int j = 0; j < 4; j++)
            bf1[j] = *(const bf16x8*)(bRd + j * 2048 + cx1);
        asm volatile("s_waitcnt lgkmcnt(0)" ::: "memory");
        __builtin_amdgcn_sched_barrier(0);
        __builtin_amdgcn_s_barrier();        // all waves done reading buf[cur]
        if (t + 2 < NT) STAGE256(cur, t + 2);

        __builtin_amdgcn_s_setprio(1);
        #pragma unroll
        for (int i = 0; i < 8; i++)
            #pragma unroll
            for (int j = 0; j < 4; j++)
                acc[i][j] = __builtin_amdgcn_mfma_f32_16x16x32_bf16(
                    af1[i], bf1[j], acc[i][j], 0, 0, 0);
        __builtin_amdgcn_s_setprio(0);
    }
    #undef STAGE256

    // epilogue: C/D layout col = lane&15, row = quad*4+v  [m89/m91]
    #pragma unroll
    for (int i = 0; i < 8; i++) {
        #pragma unroll
        for (int j = 0; j < 4; j++) {
            #pragma unroll
            for (int v = 0; v < 4; v++) {
                float val = acc[i][j][v];
                if (CLIP) val = fminf(fmaxf(val, -8.0f), 8.0f);
                int grow = bm * 256 + wr * 128 + i * 16 + quad * 4 + v;
                int gcol = bn * 256 + wc * 64 + j * 16 + row16;
                C[(size_t)grow * N + gcol] = (OUT)val;
            }
        }
    }
}

// ---------------------------------------------------------------------------
// RoPE + reorder: qkv[token][6144] -> Q[b][32][l][128] (roped),
// K[b][8][l][128] (roped), VT[b][8][128][l] (transposed copy).
// ---------------------------------------------------------------------------
__global__ __launch_bounds__(256)
void rope_reorder(const bf16* __restrict__ qkv, bf16* __restrict__ Q,
                  bf16* __restrict__ Kd, bf16* __restrict__ VT) {
    const int token = blockIdx.y;                          // 0..4095
    const int slot  = blockIdx.x * 4 + (threadIdx.x >> 6); // 0..47
    const int lane  = threadIdx.x & 63;
    const int b = token >> 11, l = token & 2047;
    const bf16* src = qkv + (size_t)token * 6144 + slot * 128;
    if (slot < 40) {
        float x1 = __bfloat162float(src[lane]);
        float x2 = __bfloat162float(src[lane + 64]);
        float inv_freq = powf(500000.0f, -(float)lane * (1.0f / 64.0f));
        float ang = (float)l * inv_freq;
        float s, c;
        sincosf(ang, &s, &c);
        float o1 = x1 * c - x2 * s;
        float o2 = x2 * c + x1 * s;
        bf16* dst;
        if (slot < 32) dst = Q  + ((size_t)(b * 32 + slot)        * 2048 + l) * 128;
        else           dst = Kd + ((size_t)(b * 8  + (slot - 32)) * 2048 + l) * 128;
        dst[lane]      = (bf16)o1;
        dst[lane + 64] = (bf16)o2;
    } else {
        bf16* dst = VT + (size_t)(b * 8 + (slot - 40)) * 128 * 2048 + l;
        dst[(size_t)lane * 2048]        = src[lane];
        dst[(size_t)(lane + 64) * 2048] = src[lane + 64];
    }
}

// ---------------------------------------------------------------------------
// Flash attention, causal, GQA 4:1 (round-4 version, verified: swapped QK^T,
// in-register softmax, T13 defer-max, T14 staging, source-side swizzle).
// ---------------------------------------------------------------------------
#define SP_STR 72

__global__ __launch_bounds__(256, 3)
void attn_kernel(const bf16* __restrict__ Q, const bf16* __restrict__ K,
                 const bf16* __restrict__ V, bf16* __restrict__ Oout) {
    const int qt = 31 - blockIdx.x;     // LPT: big tiles first
    const int bh = blockIdx.y;          // 0..63
    const int b = bh >> 5, h = bh & 31;
    const int kh = h >> 2;              // GQA: head h uses kv-head h/4
    const bf16* Qp = Q + ((size_t)(b * 32 + h) * 2048 + qt * 64) * 128;
    const bf16* Kp = K + (size_t)(b * 8 + kh) * 2048 * 128;
    const bf16* Vp = V + (size_t)(b * 8 + kh) * 128 * 2048;   // [d][l]

    __shared__ __align__(16) bf16 sK[64 * 128];   // 16 KB, rows source-swizzled
    __shared__ __align__(16) bf16 sV[128 * 64];   // 16 KB, rows source-swizzled
    __shared__ __align__(16) bf16 sP[4 * 16 * SP_STR];   // wave-private rows

    const int tid = threadIdx.x, lane = tid & 63, wave = tid >> 6;
    const int row = lane & 15, quad = lane >> 4;
    const int rx  = (row & 7) << 4;      // read-side XOR (byte bits 4..6)
    char* sKb = (char*)sK;
    char* sVb = (char*)sV;

    // Staging geometry (linear LDS dest, pre-swizzled global source):
    const int krow = tid >> 4;                   // 0..15 (row within pass)
    const int kc8  = (tid & 15) ^ (krow & 7);    // global chunk index (x8 elems)
    const int vrow = tid >> 3;                   // 0..31
    const int vc8  = (tid & 7) ^ (vrow & 7);
    const int ldst = tid * 16;                   // linear LDS byte base, +j*4096

    // Q fragments straight to registers (this wave's 16 q-rows), read once.
    bf16x8 aq[4];
    #pragma unroll
    for (int kk = 0; kk < 4; kk++)
        aq[kk] = *(const bf16x8*)(Qp + (size_t)(wave * 16 + row) * 128 + (kk * 4 + quad) * 8);

    // prologue: stage tile 0
    bf16x8 kpf[4], vpf[4];
    #pragma unroll
    for (int j = 0; j < 4; j++) {
        kpf[j] = *(const bf16x8*)(Kp + (size_t)(j * 16 + krow) * 128 + kc8 * 8);
        vpf[j] = *(const bf16x8*)(Vp + (size_t)(j * 32 + vrow) * 2048 + vc8 * 8);
    }
    #pragma unroll
    for (int j = 0; j < 4; j++) {
        *(bf16x8*)(sKb + ldst + j * 4096) = kpf[j];
        *(bf16x8*)(sVb + ldst + j * 4096) = vpf[j];
    }
    __syncthreads();

    float pm = -1e30f, pl = 0.0f;       // per-lane stats for q-row lane&15
    f32x4 o_acc[8] = {};
    const float scale = 0.08838834764831845f;   // 1/sqrt(128)

    for (int jj = 0; jj <= qt; jj++) {
        // T14: issue next tile's loads EARLY (results used only after barrier)
        if (jj < qt) {
            #pragma unroll
            for (int j = 0; j < 4; j++) {
                kpf[j] = *(const bf16x8*)(Kp + (size_t)((jj + 1) * 64 + j * 16 + krow) * 128 + kc8 * 8);
                vpf[j] = *(const bf16x8*)(Vp + (size_t)(j * 32 + vrow) * 2048 + (jj + 1) * 64 + vc8 * 8);
            }
        }

        // S^T = K Q^T (SWAPPED): A = K rows, B = Q rows.
        // D[m=quad*4+v = k-pos in subtile nt][n=lane&15 = q-row].
        f32x4 s_acc[4] = {};
        __builtin_amdgcn_s_setprio(1);
        #pragma unroll
        for (int nt = 0; nt < 4; nt++) {
            #pragma unroll
            for (int kk = 0; kk < 4; kk++) {
                bf16x8 bk = *(const bf16x8*)(sKb + (nt * 16 + row) * 256
                                             + (((kk * 4 + quad) * 16) ^ rx));
                s_acc[nt] = __builtin_amdgcn_mfma_f32_16x16x32_bf16(
                    bk, aq[kk], s_acc[nt], 0, 0, 0);
            }
        }
        __builtin_amdgcn_s_setprio(0);

        // scale + causal mask (diagonal tile only): kpos = nt*16+quad*4+v,
        // qrow(local) = wave*16 + row.
        #pragma unroll
        for (int nt = 0; nt < 4; nt++) {
            #pragma unroll
            for (int v = 0; v < 4; v++) {
                float s = s_acc[nt][v] * scale;
                if (jj == qt) {
                    int kpos = nt * 16 + quad * 4 + v;
                    int qrow = wave * 16 + row;
                    if (kpos > qrow) s = -1e30f;
                }
                s_acc[nt][v] = s;
            }
        }
        // row max: in-lane over 16 + 2 shfl (across quads)
        float m_loc = s_acc[0][0];
        #pragma unroll
        for (int nt = 0; nt < 4; nt++)
            #pragma unroll
            for (int v = 0; v < 4; v++)
                m_loc = fmaxf(m_loc, s_acc[nt][v]);
        m_loc = fmaxf(m_loc, __shfl_xor(m_loc, 16, 64));
        m_loc = fmaxf(m_loc, __shfl_xor(m_loc, 32, 64));

        // T13 defer-max: only rescale when max grew past THR=8
        if (!__all(m_loc - pm <= 8.0f)) {
            float mn = fmaxf(pm, m_loc);
            float al = __expf(pm - mn);
            pm = mn;
            pl *= al;
            float al_q[4];
            #pragma unroll
            for (int v = 0; v < 4; v++)
                al_q[v] = __shfl(al, quad * 4 + v, 64);
            #pragma unroll
            for (int dt = 0; dt < 8; dt++)
                #pragma unroll
                for (int v = 0; v < 4; v++)
                    o_acc[dt][v] *= al_q[v];
        }

        // P = exp(S - pm), lane-local row: pack 4 bf16, one b64 write per nt.
        float rs = 0.0f;
        #pragma unroll
        for (int nt = 0; nt < 4; nt++) {
            bf16x4 pw;
            #pragma unroll
            for (int v = 0; v < 4; v++) {
                float p = __expf(s_acc[nt][v] - pm);
                rs += p;
                bf16 pb = (bf16)p;
                pw[v] = *(short*)&pb;
            }
            *(bf16x4*)(sP + (wave * 16 + row) * SP_STR + nt * 16 + quad * 4) = pw;
        }
        rs += __shfl_xor(rs, 16, 64);
        rs += __shfl_xor(rs, 32, 64);
        pl += rs;

        // O += P V, pa from sP (sP[r][c] = P[r][c]), vb from swizzled sV.
        __builtin_amdgcn_s_setprio(1);
        #pragma unroll
        for (int kk = 0; kk < 2; kk++) {
            bf16x8 pa = *(const bf16x8*)(sP + (wave * 16 + row) * SP_STR + (kk * 4 + quad) * 8);
            #pragma unroll
            for (int dt = 0; dt < 8; dt++) {
                bf16x8 vb = *(const bf16x8*)(sVb + (dt * 16 + row) * 128
                                             + (((kk * 4 + quad) * 16) ^ rx));
                o_acc[dt] = __builtin_amdgcn_mfma_f32_16x16x32_bf16(
                    pa, vb, o_acc[dt], 0, 0, 0);
            }
        }
        __builtin_amdgcn_s_setprio(0);

        // T14 write-late: drain prefetched regs into LDS (linear, conflict-free)
        if (jj < qt) {
            __syncthreads();    // all waves done reading sK/sV of tile jj
            #pragma unroll
            for (int j = 0; j < 4; j++) {
                *(bf16x8*)(sKb + ldst + j * 4096) = kpf[j];
                *(bf16x8*)(sVb + ldst + j * 4096) = vpf[j];
            }
            __syncthreads();    // tile jj+1 visible
        }
    }

    // epilogue: O / l. o_acc row = quad*4+v -> fetch pl for those rows.
    float pl_q[4];
    #pragma unroll
    for (int v = 0; v < 4; v++)
        pl_q[v] = __shfl(pl, quad * 4 + v, 64);
    const int token = b * 2048 + qt * 64 + wave * 16;
    #pragma unroll
    for (int dt = 0; dt < 8; dt++) {
        #pragma unroll
        for (int v = 0; v < 4; v++) {
            float o = o_acc[dt][v] / pl_q[v];
            int trow = token + quad * 4 + v;
            Oout[(size_t)trow * 4096 + h * 128 + dt * 16 + row] = (bf16)o;
        }
    }
}

// ---------------------------------------------------------------------------
// Workspace plan (peak 128 MB; all regions fully rewritten each call):
//   0..32   xb (x as bf16)   -> later overwritten by attn output
//   32..80  Wqkvb            -> after GEMM1: Qb(32..64) Kb(64..72) VTb(72..80)
//   80..128 qkv              -> after rope:  Woutb(80..112)
// d_out is FLOAT32 (reference output dtype) — 64 MB.
// ---------------------------------------------------------------------------
extern "C" void kernel_launch(void* const* d_in, const int* in_sizes, int n_in,
                              void* d_out, int out_size, void* d_ws, size_t ws_size,
                              hipStream_t stream) {
    float* out = (float*)d_out;                // (2,2048,4096) float32

    const size_t MB = 1024 * 1024;
    char* ws = (char*)d_ws;
    bf16* xb    = (bf16*)(ws);                 // 0..32 MB
    bf16* Wqkvb = (bf16*)(ws + 32 * MB);       // 32..80 MB
    bf16* qkv   = (bf16*)(ws + 80 * MB);       // 80..128 MB
    bf16* Qb    = (bf16*)(ws + 32 * MB);       // over dead Wqkvb
    bf16* Kb    = (bf16*)(ws + 64 * MB);
    bf16* VTb   = (bf16*)(ws + 72 * MB);
    bf16* Woutb = (bf16*)(ws + 80 * MB);       // over dead qkv
    bf16* attn  = xb;                          // over dead xb

    convert_to_bf16<<<8192,  256, 0, stream>>>(d_in[0], xb,    16777216L);
    convert_to_bf16<<<12288, 256, 0, stream>>>(d_in[1], Wqkvb, 25165824L);
    // 1) qkv = clip(x @ Wqkv^T, +-8)   (bf16 out)  — 256² counted-vmcnt GEMM
    gemm256<true, bf16><<<dim3(24, 16), 512, 0, stream>>>(xb, Wqkvb, qkv, 4096, 6144, 4096);
    // 2) rope + reorder (reads 80..128, writes 32..80)
    rope_reorder<<<dim3(12, 4096), 256, 0, stream>>>(qkv, Qb, Kb, VTb);
    // (qkv now dead; stage Wout there)
    convert_to_bf16<<<8192,  256, 0, stream>>>(d_in[2], Woutb, 16777216L);
    // 3) causal GQA flash attention -> attn[token][4096] (reads 32..80, writes 0..32)
    attn_kernel<<<dim3(32, 64), 256, 0, stream>>>(Qb, Kb, VTb, attn);
    // 4) out = attn @ Wout^T            (FLOAT out -> d_out)
    gemm256<false, float><<<dim3(16, 16), 512, 0, stream>>>(attn, Woutb, out, 4096, 4096, 4096);
}

// Round 6
// 788.609 us; speedup vs baseline: 2.0831x; 1.0721x over previous
//
#include <hip/hip_runtime.h>
#include <hip/hip_bf16.h>
#include <math.h>

typedef __hip_bfloat16 bf16;
typedef __attribute__((ext_vector_type(8))) short bf16x8;   // 8 bf16 = 4 VGPRs (MFMA A/B frag)
typedef __attribute__((ext_vector_type(4))) short bf16x4;   // 4 bf16 = 8 bytes
typedef __attribute__((ext_vector_type(4))) float f32x4;    // MFMA C/D frag

__device__ __forceinline__ void glds16(const bf16* g, bf16* l) {
    __builtin_amdgcn_global_load_lds(
        (const __attribute__((address_space(1))) void*)g,
        (__attribute__((address_space(3))) void*)l, 16, 0, 0);
}

// ---------------------------------------------------------------------------
// Self-detecting convert: each wave inspects the tensor's first 128 ushorts.
// ---------------------------------------------------------------------------
__global__ __launch_bounds__(256)
void convert_to_bf16(const void* __restrict__ src, bf16* __restrict__ dst, long n) {
    const unsigned short* u16 = (const unsigned short*)src;
    int lane = threadIdx.x & 63;
    unsigned short u = u16[lane * 2];
    int e = (u >> 7) & 0xFF;
    int isf32 = __popcll(__ballot(e >= 0x86)) > 4;   // wave-uniform
    long i = ((long)blockIdx.x * 256 + threadIdx.x) * 8;
    if (i >= n) return;
    if (isf32) {
        const float* s = (const float*)src;
        bf16x8 o;
        #pragma unroll
        for (int j = 0; j < 8; j++) {
            bf16 b = (bf16)s[i + j];
            o[j] = *(short*)&b;
        }
        *(bf16x8*)(dst + i) = o;
    } else {
        *(bf16x8*)(dst + i) = *(const bf16x8*)((const bf16*)src + i);
    }
}

// ---------------------------------------------------------------------------
// GEMM round 6: 256xBN tile (BN=256 or 192), BK=64, 512 threads (8 waves,
// 2Mx4N), double-buffered LDS, T2 source-side swizzle (verified r5: 0 bank
// conflicts), T1 XCD swizzle, T5 setprio.
// NEW vs r5 (which serialized reads->MFMA with sched_barrier walls, m233's
// 2-phase stall): intra-tile pipeline —
//   issue ALL 24 (22) ds_reads; lgkmcnt(12|11) -> first group done;
//   MFMA ks0 runs while ks1 reads drain; lgkm(0); barrier; stage(t+2);
//   MFMA ks1 overlaps glds issue; counted vmcnt AFTER ks1; barrier.
// Sync ledger (G = 4+NB glds per tile):
//   prologue: stage t0,t1 -> 2G in flight; vmcnt(G) => t0 landed; barrier.
//   iter t: reads(24) ... lgkm(0) => wave done with buf[cur]; barrier =>
//     ALL done; stage(t+2) -> buf[cur]; MFMA ks1;
//     t+2<NT: vmcnt(G) => t+1 landed (t+2 flying); else vmcnt(0); barrier.
// ---------------------------------------------------------------------------
template<int BN, bool CLIP, typename OUT>
__global__ __launch_bounds__(512, 2)
void gemm256(const bf16* __restrict__ A, const bf16* __restrict__ B,
             OUT* __restrict__ C, int M, int N, int K) {
    constexpr int NB = BN / 64;          // B frags per k-step, B stage issues
    constexpr int WN = BN / 4;           // per-wave N span
    __shared__ __align__(16) bf16 sA[2][256 * 64];
    __shared__ __align__(16) bf16 sB[2][BN * 64];

    const int tid   = threadIdx.x;
    const int lane  = tid & 63;
    const int row16 = lane & 15;
    const int quad  = lane >> 4;
    const int wid   = tid >> 6;
    const int wr    = wid >> 2;          // 0..1  (M half)
    const int wc    = wid & 3;           // 0..3  (N quarter)

    // T1: XCD-aware bijective swizzle (grids here are multiples of 8)
    const int nwg  = gridDim.x * gridDim.y;
    const int orig = blockIdx.y * gridDim.x + blockIdx.x;
    const int cpx  = nwg >> 3;
    const int sw   = (orig & 7) * cpx + (orig >> 3);
    const int bn   = sw % gridDim.x;
    const int bm   = sw / gridDim.x;

    // Staging: linear LDS dest (tid*16 B), source chunk = slot ^ (row&7).
    const int srow   = tid >> 3;                 // 0..63
    const int schunk = (tid & 7) ^ (srow & 7);
    const bf16* gA = A + (size_t)(bm * 256) * K + schunk * 8;
    const bf16* gB = B + (size_t)(bn * BN) * K + schunk * 8;

    auto STAGE = [&](int u, int t) {
        #pragma unroll
        for (int q = 0; q < 4; q++)
            glds16(gA + (size_t)(q * 64 + srow) * K + t * 64,
                   &sA[u][0] + q * 4096 + tid * 8);
        #pragma unroll
        for (int q = 0; q < NB; q++)
            glds16(gB + (size_t)(q * 64 + srow) * K + t * 64,
                   &sB[u][0] + q * 4096 + tid * 8);
    };

    // Fragment read bases (bytes); chunk c of row r sits at slot c^(r&7).
    const int cx0 = ((quad) ^ (row16 & 7)) << 4;
    const int cx1 = ((4 + quad) ^ (row16 & 7)) << 4;
    const int aRowOff = (wr * 128 + row16) * 128;
    const int bRowOff = (wc * WN + row16) * 128;

    f32x4 acc[8][NB] = {};

    const int NT = K >> 6;               // 64-wide K-tiles
    STAGE(0, 0);
    STAGE(1, 1);
    if constexpr (NB == 4) asm volatile("s_waitcnt vmcnt(8)" ::: "memory");
    else                   asm volatile("s_waitcnt vmcnt(7)" ::: "memory");
    __builtin_amdgcn_sched_barrier(0);
    __builtin_amdgcn_s_barrier();

    for (int t = 0; t < NT; t++) {
        const int cur = t & 1;
        const char* aRd = (const char*)(&sA[cur][0]) + aRowOff;
        const char* bRd = (const char*)(&sB[cur][0]) + bRowOff;

        // issue ks0 reads (8+NB), then ks1 reads (8+NB), order pinned
        bf16x8 af0[8], bf0[NB], af1[8], bf1[NB];
        #pragma unroll
        for (int i = 0; i < 8; i++)
            af0[i] = *(const bf16x8*)(aRd + i * 2048 + cx0);
        #pragma unroll
        for (int j = 0; j < NB; j++)
            bf0[j] = *(const bf16x8*)(bRd + j * 2048 + cx0);
        __builtin_amdgcn_sched_barrier(0);      // group boundary (lgkm count!)
        #pragma unroll
        for (int i = 0; i < 8; i++)
            af1[i] = *(const bf16x8*)(aRd + i * 2048 + cx1);
        #pragma unroll
        for (int j = 0; j < NB; j++)
            bf1[j] = *(const bf16x8*)(bRd + j * 2048 + cx1);
        __builtin_amdgcn_sched_barrier(0);

        // wait first group only (DS completes in-order per wave)
        if constexpr (NB == 4) asm volatile("s_waitcnt lgkmcnt(12)" ::: "memory");
        else                   asm volatile("s_waitcnt lgkmcnt(11)" ::: "memory");
        __builtin_amdgcn_sched_barrier(0);

        __builtin_amdgcn_s_setprio(1);
        #pragma unroll
        for (int i = 0; i < 8; i++)
            #pragma unroll
            for (int j = 0; j < NB; j++)
                acc[i][j] = __builtin_amdgcn_mfma_f32_16x16x32_bf16(
                    af0[i], bf0[j], acc[i][j], 0, 0, 0);
        __builtin_amdgcn_s_setprio(0);
        __builtin_amdgcn_sched_barrier(0);

        asm volatile("s_waitcnt lgkmcnt(0)" ::: "memory");
        __builtin_amdgcn_sched_barrier(0);
        __builtin_amdgcn_s_barrier();        // all waves done reading buf[cur]

        if (t + 2 < NT) STAGE(cur, t + 2);
        __builtin_amdgcn_sched_barrier(0);   // keep glds issued before MFMA

        __builtin_amdgcn_s_setprio(1);
        #pragma unroll
        for (int i = 0; i < 8; i++)
            #pragma unroll
            for (int j = 0; j < NB; j++)
                acc[i][j] = __builtin_amdgcn_mfma_f32_16x16x32_bf16(
                    af1[i], bf1[j], acc[i][j], 0, 0, 0);
        __builtin_amdgcn_s_setprio(0);
        __builtin_amdgcn_sched_barrier(0);

        if (t + 2 < NT) {
            if constexpr (NB == 4) asm volatile("s_waitcnt vmcnt(8)" ::: "memory");
            else                   asm volatile("s_waitcnt vmcnt(7)" ::: "memory");
        } else {
            asm volatile("s_waitcnt vmcnt(0)" ::: "memory");
        }
        __builtin_amdgcn_sched_barrier(0);
        __builtin_amdgcn_s_barrier();        // buf[cur^1] (tile t+1) visible
    }

    // epilogue: C/D layout col = lane&15, row = quad*4+v  [m89/m91]
    #pragma unroll
    for (int i = 0; i < 8; i++) {
        #pragma unroll
        for (int j = 0; j < NB; j++) {
            #pragma unroll
            for (int v = 0; v < 4; v++) {
                float val = acc[i][j][v];
                if (CLIP) val = fminf(fmaxf(val, -8.0f), 8.0f);
                int grow = bm * 256 + wr * 128 + i * 16 + quad * 4 + v;
                int gcol = bn * BN + wc * WN + j * 16 + row16;
                C[(size_t)grow * N + gcol] = (OUT)val;
            }
        }
    }
}

// ---------------------------------------------------------------------------
// RoPE + reorder: qkv[token][6144] -> Q[b][32][l][128] (roped),
// K[b][8][l][128] (roped), VT[b][8][128][l] (transposed copy).
// ---------------------------------------------------------------------------
__global__ __launch_bounds__(256)
void rope_reorder(const bf16* __restrict__ qkv, bf16* __restrict__ Q,
                  bf16* __restrict__ Kd, bf16* __restrict__ VT) {
    const int token = blockIdx.y;                          // 0..4095
    const int slot  = blockIdx.x * 4 + (threadIdx.x >> 6); // 0..47
    const int lane  = threadIdx.x & 63;
    const int b = token >> 11, l = token & 2047;
    const bf16* src = qkv + (size_t)token * 6144 + slot * 128;
    if (slot < 40) {
        float x1 = __bfloat162float(src[lane]);
        float x2 = __bfloat162float(src[lane + 64]);
        float inv_freq = powf(500000.0f, -(float)lane * (1.0f / 64.0f));
        float ang = (float)l * inv_freq;
        float s, c;
        sincosf(ang, &s, &c);
        float o1 = x1 * c - x2 * s;
        float o2 = x2 * c + x1 * s;
        bf16* dst;
        if (slot < 32) dst = Q  + ((size_t)(b * 32 + slot)        * 2048 + l) * 128;
        else           dst = Kd + ((size_t)(b * 8  + (slot - 32)) * 2048 + l) * 128;
        dst[lane]      = (bf16)o1;
        dst[lane + 64] = (bf16)o2;
    } else {
        bf16* dst = VT + (size_t)(b * 8 + (slot - 40)) * 128 * 2048 + l;
        dst[(size_t)lane * 2048]        = src[lane];
        dst[(size_t)(lane + 64) * 2048] = src[lane + 64];
    }
}

// ---------------------------------------------------------------------------
// Flash attention, causal, GQA 4:1 (round-4 version, verified: swapped QK^T,
// in-register softmax, T13 defer-max, T14 staging, source-side swizzle).
// ---------------------------------------------------------------------------
#define SP_STR 72

__global__ __launch_bounds__(256, 3)
void attn_kernel(const bf16* __restrict__ Q, const bf16* __restrict__ K,
                 const bf16* __restrict__ V, bf16* __restrict__ Oout) {
    const int qt = 31 - blockIdx.x;     // LPT: big tiles first
    const int bh = blockIdx.y;          // 0..63
    const int b = bh >> 5, h = bh & 31;
    const int kh = h >> 2;              // GQA: head h uses kv-head h/4
    const bf16* Qp = Q + ((size_t)(b * 32 + h) * 2048 + qt * 64) * 128;
    const bf16* Kp = K + (size_t)(b * 8 + kh) * 2048 * 128;
    const bf16* Vp = V + (size_t)(b * 8 + kh) * 128 * 2048;   // [d][l]

    __shared__ __align__(16) bf16 sK[64 * 128];   // 16 KB, rows source-swizzled
    __shared__ __align__(16) bf16 sV[128 * 64];   // 16 KB, rows source-swizzled
    __shared__ __align__(16) bf16 sP[4 * 16 * SP_STR];   // wave-private rows

    const int tid = threadIdx.x, lane = tid & 63, wave = tid >> 6;
    const int row = lane & 15, quad = lane >> 4;
    const int rx  = (row & 7) << 4;      // read-side XOR (byte bits 4..6)
    char* sKb = (char*)sK;
    char* sVb = (char*)sV;

    // Staging geometry (linear LDS dest, pre-swizzled global source):
    const int krow = tid >> 4;                   // 0..15 (row within pass)
    const int kc8  = (tid & 15) ^ (krow & 7);    // global chunk index (x8 elems)
    const int vrow = tid >> 3;                   // 0..31
    const int vc8  = (tid & 7) ^ (vrow & 7);
    const int ldst = tid * 16;                   // linear LDS byte base, +j*4096

    // Q fragments straight to registers (this wave's 16 q-rows), read once.
    bf16x8 aq[4];
    #pragma unroll
    for (int kk = 0; kk < 4; kk++)
        aq[kk] = *(const bf16x8*)(Qp + (size_t)(wave * 16 + row) * 128 + (kk * 4 + quad) * 8);

    // prologue: stage tile 0
    bf16x8 kpf[4], vpf[4];
    #pragma unroll
    for (int j = 0; j < 4; j++) {
        kpf[j] = *(const bf16x8*)(Kp + (size_t)(j * 16 + krow) * 128 + kc8 * 8);
        vpf[j] = *(const bf16x8*)(Vp + (size_t)(j * 32 + vrow) * 2048 + vc8 * 8);
    }
    #pragma unroll
    for (int j = 0; j < 4; j++) {
        *(bf16x8*)(sKb + ldst + j * 4096) = kpf[j];
        *(bf16x8*)(sVb + ldst + j * 4096) = vpf[j];
    }
    __syncthreads();

    float pm = -1e30f, pl = 0.0f;       // per-lane stats for q-row lane&15
    f32x4 o_acc[8] = {};
    const float scale = 0.08838834764831845f;   // 1/sqrt(128)

    for (int jj = 0; jj <= qt; jj++) {
        // T14: issue next tile's loads EARLY (results used only after barrier)
        if (jj < qt) {
            #pragma unroll
            for (int j = 0; j < 4; j++) {
                kpf[j] = *(const bf16x8*)(Kp + (size_t)((jj + 1) * 64 + j * 16 + krow) * 128 + kc8 * 8);
                vpf[j] = *(const bf16x8*)(Vp + (size_t)(j * 32 + vrow) * 2048 + (jj + 1) * 64 + vc8 * 8);
            }
        }

        // S^T = K Q^T (SWAPPED): A = K rows, B = Q rows.
        // D[m=quad*4+v = k-pos in subtile nt][n=lane&15 = q-row].
        f32x4 s_acc[4] = {};
        __builtin_amdgcn_s_setprio(1);
        #pragma unroll
        for (int nt = 0; nt < 4; nt++) {
            #pragma unroll
            for (int kk = 0; kk < 4; kk++) {
                bf16x8 bk = *(const bf16x8*)(sKb + (nt * 16 + row) * 256
                                             + (((kk * 4 + quad) * 16) ^ rx));
                s_acc[nt] = __builtin_amdgcn_mfma_f32_16x16x32_bf16(
                    bk, aq[kk], s_acc[nt], 0, 0, 0);
            }
        }
        __builtin_amdgcn_s_setprio(0);

        // scale + causal mask (diagonal tile only): kpos = nt*16+quad*4+v,
        // qrow(local) = wave*16 + row.
        #pragma unroll
        for (int nt = 0; nt < 4; nt++) {
            #pragma unroll
            for (int v = 0; v < 4; v++) {
                float s = s_acc[nt][v] * scale;
                if (jj == qt) {
                    int kpos = nt * 16 + quad * 4 + v;
                    int qrow = wave * 16 + row;
                    if (kpos > qrow) s = -1e30f;
                }
                s_acc[nt][v] = s;
            }
        }
        // row max: in-lane over 16 + 2 shfl (across quads)
        float m_loc = s_acc[0][0];
        #pragma unroll
        for (int nt = 0; nt < 4; nt++)
            #pragma unroll
            for (int v = 0; v < 4; v++)
                m_loc = fmaxf(m_loc, s_acc[nt][v]);
        m_loc = fmaxf(m_loc, __shfl_xor(m_loc, 16, 64));
        m_loc = fmaxf(m_loc, __shfl_xor(m_loc, 32, 64));

        // T13 defer-max: only rescale when max grew past THR=8
        if (!__all(m_loc - pm <= 8.0f)) {
            float mn = fmaxf(pm, m_loc);
            float al = __expf(pm - mn);
            pm = mn;
            pl *= al;
            float al_q[4];
            #pragma unroll
            for (int v = 0; v < 4; v++)
                al_q[v] = __shfl(al, quad * 4 + v, 64);
            #pragma unroll
            for (int dt = 0; dt < 8; dt++)
                #pragma unroll
                for (int v = 0; v < 4; v++)
                    o_acc[dt][v] *= al_q[v];
        }

        // P = exp(S - pm), lane-local row: pack 4 bf16, one b64 write per nt.
        float rs = 0.0f;
        #pragma unroll
        for (int nt = 0; nt < 4; nt++) {
            bf16x4 pw;
            #pragma unroll
            for (int v = 0; v < 4; v++) {
                float p = __expf(s_acc[nt][v] - pm);
                rs += p;
                bf16 pb = (bf16)p;
                pw[v] = *(short*)&pb;
            }
            *(bf16x4*)(sP + (wave * 16 + row) * SP_STR + nt * 16 + quad * 4) = pw;
        }
        rs += __shfl_xor(rs, 16, 64);
        rs += __shfl_xor(rs, 32, 64);
        pl += rs;

        // O += P V, pa from sP (sP[r][c] = P[r][c]), vb from swizzled sV.
        __builtin_amdgcn_s_setprio(1);
        #pragma unroll
        for (int kk = 0; kk < 2; kk++) {
            bf16x8 pa = *(const bf16x8*)(sP + (wave * 16 + row) * SP_STR + (kk * 4 + quad) * 8);
            #pragma unroll
            for (int dt = 0; dt < 8; dt++) {
                bf16x8 vb = *(const bf16x8*)(sVb + (dt * 16 + row) * 128
                                             + (((kk * 4 + quad) * 16) ^ rx));
                o_acc[dt] = __builtin_amdgcn_mfma_f32_16x16x32_bf16(
                    pa, vb, o_acc[dt], 0, 0, 0);
            }
        }
        __builtin_amdgcn_s_setprio(0);

        // T14 write-late: drain prefetched regs into LDS (linear, conflict-free)
        if (jj < qt) {
            __syncthreads();    // all waves done reading sK/sV of tile jj
            #pragma unroll
            for (int j = 0; j < 4; j++) {
                *(bf16x8*)(sKb + ldst + j * 4096) = kpf[j];
                *(bf16x8*)(sVb + ldst + j * 4096) = vpf[j];
            }
            __syncthreads();    // tile jj+1 visible
        }
    }

    // epilogue: O / l. o_acc row = quad*4+v -> fetch pl for those rows.
    float pl_q[4];
    #pragma unroll
    for (int v = 0; v < 4; v++)
        pl_q[v] = __shfl(pl, quad * 4 + v, 64);
    const int token = b * 2048 + qt * 64 + wave * 16;
    #pragma unroll
    for (int dt = 0; dt < 8; dt++) {
        #pragma unroll
        for (int v = 0; v < 4; v++) {
            float o = o_acc[dt][v] / pl_q[v];
            int trow = token + quad * 4 + v;
            Oout[(size_t)trow * 4096 + h * 128 + dt * 16 + row] = (bf16)o;
        }
    }
}

// ---------------------------------------------------------------------------
// Workspace plan (peak 128 MB; all regions fully rewritten each call):
//   0..32   xb (x as bf16)   -> later overwritten by attn output
//   32..80  Wqkvb            -> after GEMM1: Qb(32..64) Kb(64..72) VTb(72..80)
//   80..128 qkv              -> after rope:  Woutb(80..112)
// d_out is FLOAT32 (reference output dtype) — 64 MB.
// ---------------------------------------------------------------------------
extern "C" void kernel_launch(void* const* d_in, const int* in_sizes, int n_in,
                              void* d_out, int out_size, void* d_ws, size_t ws_size,
                              hipStream_t stream) {
    float* out = (float*)d_out;                // (2,2048,4096) float32

    const size_t MB = 1024 * 1024;
    char* ws = (char*)d_ws;
    bf16* xb    = (bf16*)(ws);                 // 0..32 MB
    bf16* Wqkvb = (bf16*)(ws + 32 * MB);       // 32..80 MB
    bf16* qkv   = (bf16*)(ws + 80 * MB);       // 80..128 MB
    bf16* Qb    = (bf16*)(ws + 32 * MB);       // over dead Wqkvb
    bf16* Kb    = (bf16*)(ws + 64 * MB);
    bf16* VTb   = (bf16*)(ws + 72 * MB);
    bf16* Woutb = (bf16*)(ws + 80 * MB);       // over dead qkv
    bf16* attn  = xb;                          // over dead xb

    convert_to_bf16<<<8192,  256, 0, stream>>>(d_in[0], xb,    16777216L);
    convert_to_bf16<<<12288, 256, 0, stream>>>(d_in[1], Wqkvb, 25165824L);
    // 1) qkv = clip(x @ Wqkv^T, +-8)  — BN=192: 32x16 grid = 2 FULL rounds
    gemm256<192, true, bf16><<<dim3(32, 16), 512, 0, stream>>>(xb, Wqkvb, qkv, 4096, 6144, 4096);
    // 2) rope + reorder (reads 80..128, writes 32..80)
    rope_reorder<<<dim3(12, 4096), 256, 0, stream>>>(qkv, Qb, Kb, VTb);
    // (qkv now dead; stage Wout there)
    convert_to_bf16<<<8192,  256, 0, stream>>>(d_in[2], Woutb, 16777216L);
    // 3) causal GQA flash attention -> attn[token][4096] (reads 32..80, writes 0..32)
    attn_kernel<<<dim3(32, 64), 256, 0, stream>>>(Qb, Kb, VTb, attn);
    // 4) out = attn @ Wout^T            (FLOAT out -> d_out)
    gemm256<256, false, float><<<dim3(16, 16), 512, 0, stream>>>(attn, Woutb, out, 4096, 4096, 4096);
}